// Round 6
// baseline (1214.062 us; speedup 1.0000x reference)
//
#include <hip/hip_runtime.h>
#include <hip/hip_bf16.h>
#include <math.h>

// Problem constants
#define NB   2
#define NT   4096
#define ND   2048
#define NH   16
#define NDK  128
#define NCL  512
#define NNC  8
#define NTOK 8192
#define SCALING 0.08838834764831845f  // 128^-0.5

typedef unsigned short u16;
typedef short short8 __attribute__((ext_vector_type(8)));
typedef unsigned short ushort8 __attribute__((ext_vector_type(8)));
typedef float f32x4 __attribute__((ext_vector_type(4)));
typedef float float4v __attribute__((ext_vector_type(4)));
typedef short short4v __attribute__((ext_vector_type(4)));

__device__ __forceinline__ float bf2f(u16 u) {
    union { unsigned int i; float f; } v; v.i = ((unsigned int)u) << 16; return v.f;
}
__device__ __forceinline__ u16 f2bf(float f) {
    union { float f; unsigned int i; } v; v.f = f;
    unsigned int r = v.i + 0x7FFFu + ((v.i >> 16) & 1u);
    return (u16)(r >> 16);
}

// async global->LDS, 16B per lane (used only by the 128^2 core / k_inner).
__device__ __forceinline__ void gload16(const void* g, void* l) {
    __builtin_amdgcn_global_load_lds(
        (const __attribute__((address_space(1))) unsigned int*)g,
        (__attribute__((address_space(3))) unsigned int*)l, 16, 0, 0);
}

#define MFMA16(acc_, a_, b_) acc_ = __builtin_amdgcn_mfma_f32_16x16x32_bf16(a_, b_, acc_, 0, 0, 0)
#define SBAR  asm volatile("s_barrier" ::: "memory")

// ===========================================================================
// 256x256-tile 8-phase GEMM core, REGISTER-STAGED (T14):
//   C(256x256) = A(256xK) * B(256xK)^T, A/B row-major bf16, SAME leading dim.
//   512 threads = 8 waves (2 M x 4 N), per-wave 128x64 output, acc[8][4].
//   LDS: 4 distinct arrays A0/A1/B0/B1 (32 KB each). BK=64.
//   Staging: p0 issues 8 global_load_dwordx4 -> VGPRs for tile G+1 (precise
//   per-register vmcnt tracking -- avoids the conservative LDS-DMA waitcnt
//   the compiler emits for global_load_lds); p2 ds_writes A(G+1); p3
//   ds_writes B(G+1) + lgkmcnt(0) before the tile-final barrier.
//   T2: XOR swizzle unit^=(row&7) applied on global SOURCE + LDS READ
//   (LDS stores linear). T5: setprio around MFMA clusters.
// ===========================================================================

__device__ __forceinline__ void tile4(
    int G, int nkt,
    const u16* Aop, const u16* Bop,
    const size_t* off, const int* lof,
    int arow, int brow, int uc0, int uc1,
    u16* ARd, u16* BRd, u16* AWr, u16* BWr,
    f32x4 acc[8][4])
{
    short8 a[4][2], bA[2][2], bB[2][2];
    int4 ra[4], rb[4];
    const bool pf = (G + 1 < nkt);

    // ---- p0: read a(m0) + bA(n0); ISSUE global loads for tile G+1
#pragma unroll
    for (int mf = 0; mf < 4; ++mf) {
        a[mf][0] = *(const short8*)(ARd + (size_t)(arow + mf * 16) * 64 + uc0);
        a[mf][1] = *(const short8*)(ARd + (size_t)(arow + mf * 16) * 64 + uc1);
    }
#pragma unroll
    for (int nf = 0; nf < 2; ++nf) {
        bA[nf][0] = *(const short8*)(BRd + (size_t)(brow + nf * 16) * 64 + uc0);
        bA[nf][1] = *(const short8*)(BRd + (size_t)(brow + nf * 16) * 64 + uc1);
    }
    if (pf) {
        const u16* Ag = Aop + (size_t)(G + 1) * 64;
        const u16* Bg = Bop + (size_t)(G + 1) * 64;
#pragma unroll
        for (int j = 0; j < 4; ++j) ra[j] = *(const int4*)(Ag + off[j]);
#pragma unroll
        for (int j = 0; j < 4; ++j) rb[j] = *(const int4*)(Bg + off[j]);
    }
    SBAR;
    __builtin_amdgcn_s_setprio(1);
#pragma unroll
    for (int mf = 0; mf < 4; ++mf)
#pragma unroll
        for (int nf = 0; nf < 2; ++nf) {
            MFMA16(acc[mf][nf], a[mf][0], bA[nf][0]);
            MFMA16(acc[mf][nf], a[mf][1], bA[nf][1]);
        }
    __builtin_amdgcn_s_setprio(0);
    SBAR;

    // ---- p1: read bB(n1)
#pragma unroll
    for (int nf = 0; nf < 2; ++nf) {
        bB[nf][0] = *(const short8*)(BRd + (size_t)(brow + 32 + nf * 16) * 64 + uc0);
        bB[nf][1] = *(const short8*)(BRd + (size_t)(brow + 32 + nf * 16) * 64 + uc1);
    }
    SBAR;
    __builtin_amdgcn_s_setprio(1);
#pragma unroll
    for (int mf = 0; mf < 4; ++mf)
#pragma unroll
        for (int nf = 0; nf < 2; ++nf) {
            MFMA16(acc[mf][2 + nf], a[mf][0], bB[nf][0]);
            MFMA16(acc[mf][2 + nf], a[mf][1], bB[nf][1]);
        }
    __builtin_amdgcn_s_setprio(0);
    SBAR;

    // ---- p2: read a(m1); ds_write A(G+1) -> AWr (readers of AWr done last tile)
#pragma unroll
    for (int mf = 0; mf < 4; ++mf) {
        a[mf][0] = *(const short8*)(ARd + (size_t)(arow + 64 + mf * 16) * 64 + uc0);
        a[mf][1] = *(const short8*)(ARd + (size_t)(arow + 64 + mf * 16) * 64 + uc1);
    }
    if (pf) {
#pragma unroll
        for (int j = 0; j < 4; ++j) *(int4*)((char*)AWr + lof[j]) = ra[j];
    }
    SBAR;
    __builtin_amdgcn_s_setprio(1);
#pragma unroll
    for (int mf = 0; mf < 4; ++mf)
#pragma unroll
        for (int nf = 0; nf < 2; ++nf) {
            MFMA16(acc[4 + mf][2 + nf], a[mf][0], bB[nf][0]);
            MFMA16(acc[4 + mf][2 + nf], a[mf][1], bB[nf][1]);
        }
    __builtin_amdgcn_s_setprio(0);
    SBAR;

    // ---- p3: ds_write B(G+1) -> BWr; drain LDS writes before final barrier
    if (pf) {
#pragma unroll
        for (int j = 0; j < 4; ++j) *(int4*)((char*)BWr + lof[j]) = rb[j];
        asm volatile("s_waitcnt lgkmcnt(0)" ::: "memory");
    }
    SBAR;
    __builtin_amdgcn_s_setprio(1);
#pragma unroll
    for (int mf = 0; mf < 4; ++mf)
#pragma unroll
        for (int nf = 0; nf < 2; ++nf) {
            MFMA16(acc[4 + mf][nf], a[mf][0], bA[nf][0]);
            MFMA16(acc[4 + mf][nf], a[mf][1], bA[nf][1]);
        }
    __builtin_amdgcn_s_setprio(0);
    SBAR;
}

__device__ __forceinline__ void gemm256_core(
    const u16* Aop, const u16* Bop,
    int ld, int nkt,
    u16* A0, u16* A1, u16* B0, u16* B1, f32x4 acc[8][4])
{
    const int tid  = threadIdx.x;
    const int lane = tid & 63;
    const int lr   = lane & 15;
    const int lg   = lane >> 4;
    const int wid  = tid >> 6;
    const int wm   = wid >> 2;        // 0..1
    const int wn   = wid & 3;         // 0..3

    const int swz  = lr & 7;
    const int uc0  = ((0 * 4 + lg) ^ swz) * 8;   // kk=0 read unit (elems)
    const int uc1  = ((1 * 4 + lg) ^ swz) * 8;   // kk=1
    const int arow = wm * 128 + lr;
    const int brow = wn * 64 + lr;

    // per-thread staging chunk offsets: j = {h0,c0},{h0,c1},{h1,c0},{h1,c1}
    size_t off[4];
    int lof[4];
#pragma unroll
    for (int j = 0; j < 4; ++j) {
        int c = tid + (j & 1) * 512;          // 0..1023
        int row = c >> 3, u = c & 7;
        int h = j >> 1;
        off[j] = (size_t)(h * 128 + row) * ld + ((u ^ (row & 7)) * 8);
        lof[j] = h * 16384 + c * 16;          // byte offset in LDS tile
    }

    // prologue: tile 0 -> A0/B0 via regs
    {
        int4 ta[4], tb[4];
#pragma unroll
        for (int j = 0; j < 4; ++j) ta[j] = *(const int4*)(Aop + off[j]);
#pragma unroll
        for (int j = 0; j < 4; ++j) tb[j] = *(const int4*)(Bop + off[j]);
#pragma unroll
        for (int j = 0; j < 4; ++j) *(int4*)((char*)A0 + lof[j]) = ta[j];
#pragma unroll
        for (int j = 0; j < 4; ++j) *(int4*)((char*)B0 + lof[j]) = tb[j];
        asm volatile("s_waitcnt lgkmcnt(0)" ::: "memory");
        SBAR;
    }

    for (int G = 0; G < nkt; G += 2) {
        tile4(G,     nkt, Aop, Bop, off, lof, arow, brow, uc0, uc1,
              A0, B0, A1, B1, acc);
        tile4(G + 1, nkt, Aop, Bop, off, lof, arow, brow, uc0, uc1,
              A1, B1, A0, B0, acc);
    }
}

// ---------------------------------------------------------------------------
// Old 128x128 core (kept for the small GEMMs: kv, combine)
// ---------------------------------------------------------------------------
__device__ __forceinline__ void gemm_bt_core(
    const u16* __restrict__ A, const u16* __restrict__ Bm,
    int lda, int ldb, int K, u16* As, u16* Bs, f32x4 acc[4][4])
{
    const int tid  = threadIdx.x;
    const int lane = tid & 63;
    const int lr   = lane & 15;
    const int lg   = lane >> 4;
    const int wid  = tid >> 6;
    const int wr   = (wid >> 1) * 64;
    const int wc   = (wid & 1) * 64;
    for (int kt = 0; kt < K; kt += 64) {
#pragma unroll
        for (int i = 0; i < 4; ++i) {
            int c = tid + i * 256;
            int row = c >> 3, col = (c & 7) * 8;
            gload16(A  + (size_t)row * lda + kt + col, (char*)As + (size_t)c * 16);
            gload16(Bm + (size_t)row * ldb + kt + col, (char*)Bs + (size_t)c * 16);
        }
        __syncthreads();
#pragma unroll
        for (int kk = 0; kk < 2; ++kk) {
            short8 a[4], b[4];
#pragma unroll
            for (int m = 0; m < 4; ++m)
                a[m] = *(const short8*)(As + (wr + m * 16 + lr) * 64 + kk * 32 + lg * 8);
#pragma unroll
            for (int n = 0; n < 4; ++n)
                b[n] = *(const short8*)(Bs + (wc + n * 16 + lr) * 64 + kk * 32 + lg * 8);
#pragma unroll
            for (int m = 0; m < 4; ++m)
#pragma unroll
                for (int n = 0; n < 4; ++n)
                    acc[m][n] = __builtin_amdgcn_mfma_f32_16x16x32_bf16(a[m], b[n], acc[m][n], 0, 0, 0);
        }
        __syncthreads();
    }
}

// ---------------------------------------------------------------------------
// fp32 -> bf16 convert
// ---------------------------------------------------------------------------
__global__ __launch_bounds__(256) void k_f2bf(const float* __restrict__ src,
                                              u16* __restrict__ dst, int n4)
{
    int i = blockIdx.x * blockDim.x + threadIdx.x;
    int stride = gridDim.x * blockDim.x;
    for (int j = i; j < n4; j += stride) {
        float4v f = *(const float4v*)(src + (size_t)j * 4);
        short4v o;
        o.x = (short)f2bf(f.x); o.y = (short)f2bf(f.y);
        o.z = (short)f2bf(f.z); o.w = (short)f2bf(f.w);
        *(short4v*)(dst + (size_t)j * 4) = o;
    }
}

// ---------------------------------------------------------------------------
// GEMM1 (256^2 8-phase): [8192 x 2048] x [8192 x 2048]^T; epilogue fuses
// bias + rotary (q,k), k-scaling, decay-weighted transposed krwT, vT, g.
// ---------------------------------------------------------------------------
__global__ __launch_bounds__(512, 2) void k_gemm1(
    const u16* __restrict__ xb, const u16* __restrict__ wb,
    const float* __restrict__ bq, const float* __restrict__ bk,
    const float* __restrict__ bv, const float* __restrict__ bg,
    const float* __restrict__ sinp, const float* __restrict__ cosp,
    const float* __restrict__ maskp,
    u16* __restrict__ qro, u16* __restrict__ kro, u16* __restrict__ krwT,
    u16* __restrict__ vT, u16* __restrict__ glin)
{
    __shared__ __align__(16) u16 A0[256 * 64];
    __shared__ __align__(16) u16 A1[256 * 64];
    __shared__ __align__(16) u16 B0[256 * 64];
    __shared__ __align__(16) u16 B1[256 * 64];
    f32x4 acc[8][4];
#pragma unroll
    for (int m = 0; m < 8; ++m)
#pragma unroll
        for (int n = 0; n < 4; ++n) acc[m][n] = (f32x4){0.f, 0.f, 0.f, 0.f};

    // T1 bijective XCD swizzle: nwg=1024, 1024%8==0
    int bid = blockIdx.x;
    int swzb = (bid & 7) * 128 + (bid >> 3);
    int mt = swzb >> 5, nt = swzb & 31;          // 32 x 32 tiles of 256

    gemm256_core(xb + (size_t)mt * 256 * ND, wb + (size_t)nt * 256 * ND,
                 ND, ND / 64, A0, A1, B0, B1, acc);

    int tid = threadIdx.x, lane = tid & 63, lr = lane & 15, lg = lane >> 4, wid = tid >> 6;
    int wm = wid >> 2, wn = wid & 3;
    int which = nt >> 3;   // 0:q 1:k 2:v 3:g (uniform per block)

    if (which <= 1) {
        const float* bias = (which == 0) ? bq : bk;
#pragma unroll
        for (int mf = 0; mf < 8; ++mf) {
#pragma unroll
            for (int nf = 0; nf < 4; ++nf) {
#pragma unroll
                for (int r = 0; r < 4; ++r) {
                    int row = mt * 256 + wm * 128 + mf * 16 + lg * 4 + r;
                    int col = nt * 256 + wn * 64 + nf * 16 + lr;
                    int f = col & 2047, h = f >> 7, d = f & 127;
                    int b = row >> 12, t = row & 4095, cn = t >> 9, cl = t & 511;
                    float v = acc[mf][nf][r] + bias[f];
                    if (which == 1) v *= SCALING;
                    float sv = sinp[(size_t)t * NDK + d];
                    float cv = cosp[(size_t)t * NDK + d];
                    float vp = __shfl_xor(v, 1);          // partner feature (col^1)
                    float rot = (lr & 1) ? vp : -vp;      // rotate_every_two
                    float o = v * cv + rot * sv;
                    size_t chbase = (size_t)(b * NNC + cn) * NH + h;
                    if (which == 0) {
                        qro[(chbase * NCL + cl) * NDK + d] = f2bf(o);
                    } else {
                        kro[(chbase * NCL + cl) * NDK + d] = f2bf(o);
                        float w = maskp[((size_t)h * NCL + (NCL - 1)) * NCL + cl];
                        krwT[(chbase * NDK + d) * NCL + cl] = f2bf(o * w);
                    }
                }
            }
        }
    } else {
#pragma unroll
        for (int mf = 0; mf < 8; ++mf) {
#pragma unroll
            for (int nf = 0; nf < 4; ++nf) {
#pragma unroll
                for (int r = 0; r < 4; ++r) {
                    int row = mt * 256 + wm * 128 + mf * 16 + lg * 4 + r;
                    int col = nt * 256 + wn * 64 + nf * 16 + lr;
                    int f = col & 2047;
                    float v = acc[mf][nf][r];
                    if (which == 2) {
                        int h = f >> 7, d = f & 127;
                        int b = row >> 12, t = row & 4095, cn = t >> 9, cl = t & 511;
                        vT[(((size_t)(b * NNC + cn) * NH + h) * NDK + d) * NCL + cl] = f2bf(v + bv[f]);
                    } else {
                        glin[(size_t)row * ND + f] = f2bf(v + bg[f]);
                    }
                }
            }
        }
    }
}

// ---------------------------------------------------------------------------
// GEMM2 (256^2 8-phase): y[8192x2048] x wo[2048x2048]^T + bo -> fp32 out
// ---------------------------------------------------------------------------
__global__ __launch_bounds__(512, 2) void k_gemm2(
    const u16* __restrict__ y, const u16* __restrict__ wob,
    const float* __restrict__ bo, float* __restrict__ out)
{
    __shared__ __align__(16) u16 A0[256 * 64];
    __shared__ __align__(16) u16 A1[256 * 64];
    __shared__ __align__(16) u16 B0[256 * 64];
    __shared__ __align__(16) u16 B1[256 * 64];
    f32x4 acc[8][4];
#pragma unroll
    for (int m = 0; m < 8; ++m)
#pragma unroll
        for (int n = 0; n < 4; ++n) acc[m][n] = (f32x4){0.f, 0.f, 0.f, 0.f};

    // nwg = 256, 256%8==0
    int bid = blockIdx.x;
    int swzb = (bid & 7) * 32 + (bid >> 3);
    int mt = swzb >> 3, nt = swzb & 7;           // 32 x 8 tiles of 256

    gemm256_core(y + (size_t)mt * 256 * ND, wob + (size_t)nt * 256 * ND,
                 ND, ND / 64, A0, A1, B0, B1, acc);

    int tid = threadIdx.x, lane = tid & 63, lr = lane & 15, lg = lane >> 4, wid = tid >> 6;
    int wm = wid >> 2, wn = wid & 3;
#pragma unroll
    for (int mf = 0; mf < 8; ++mf)
#pragma unroll
        for (int nf = 0; nf < 4; ++nf)
#pragma unroll
            for (int r = 0; r < 4; ++r) {
                int row = mt * 256 + wm * 128 + mf * 16 + lg * 4 + r;
                int col = nt * 256 + wn * 64 + nf * 16 + lr;
                out[(size_t)row * ND + col] = acc[mf][nf][r] + bo[col];
            }
}

// ---------------------------------------------------------------------------
// Inner retention (unchanged): P = (Q K^T)*mask ; s=row|P|sum ; iraw = P @ V.
// ---------------------------------------------------------------------------
__global__ __launch_bounds__(256) void k_inner(
    const u16* __restrict__ qr, const u16* __restrict__ kr,
    const u16* __restrict__ vT, const float* __restrict__ mask,
    float* __restrict__ iraw, float* __restrict__ iscale)
{
    __shared__ __align__(16) u16 Qs[128 * 128];
    __shared__ __align__(16) u16 Ks[32 * 128];
    __shared__ __align__(16) u16 Vs[128 * 32];
    __shared__ __align__(16) u16 Ps[4][32 * 32];
    __shared__ float sl[128];

    int qt = blockIdx.x, bnh = blockIdx.y;
    int h = bnh & 15;
    const u16* Q = qr + (size_t)bnh * NCL * NDK + (size_t)qt * 128 * NDK;
    const u16* K = kr + (size_t)bnh * NCL * NDK;
    const u16* V = vT + (size_t)bnh * NDK * NCL;
    const float* M = mask + (size_t)h * NCL * NCL + (size_t)qt * 128 * NCL;

    int tid = threadIdx.x, lane = tid & 63, lr = lane & 15, lg = lane >> 4, wid = tid >> 6;
    if (tid < 128) sl[tid] = 0.f;
#pragma unroll
    for (int i = 0; i < 8; ++i) {
        int c = tid + i * 256;
        gload16(Q + (size_t)c * 8, (char*)Qs + (size_t)c * 16);
    }
    __syncthreads();

    short8 aq[2][4];
#pragma unroll
    for (int i = 0; i < 2; ++i)
#pragma unroll
        for (int kk = 0; kk < 4; ++kk)
            aq[i][kk] = *(const short8*)(Qs + (wid * 32 + i * 16 + lr) * 128 + kk * 32 + lg * 8);

    f32x4 acc[2][8];
#pragma unroll
    for (int i = 0; i < 2; ++i)
#pragma unroll
        for (int n = 0; n < 8; ++n) acc[i][n] = (f32x4){0.f, 0.f, 0.f, 0.f};

    int msteps = qt * 4 + 4;
    for (int ms = 0; ms < msteps; ++ms) {
        int mb = ms * 32;
#pragma unroll
        for (int i = 0; i < 2; ++i) {
            int c = tid + i * 256;
            int row = c >> 4, cc = (c & 15) * 8;
            gload16(K + (size_t)(mb + row) * NDK + cc, (char*)Ks + (size_t)c * 16);
        }
#pragma unroll
        for (int i = 0; i < 2; ++i) {
            int c = tid + i * 256;
            int row = c >> 2, cc = (c & 3) * 8;
            gload16(V + (size_t)row * NCL + mb + cc, (char*)Vs + (size_t)c * 16);
        }
        __syncthreads();

        f32x4 pa[2][2];
#pragma unroll
        for (int i = 0; i < 2; ++i) { pa[i][0] = (f32x4){0.f,0.f,0.f,0.f}; pa[i][1] = (f32x4){0.f,0.f,0.f,0.f}; }
#pragma unroll
        for (int kk = 0; kk < 4; ++kk) {
            short8 bk0 = *(const short8*)(Ks + (lr) * 128 + kk * 32 + lg * 8);
            short8 bk1 = *(const short8*)(Ks + (16 + lr) * 128 + kk * 32 + lg * 8);
#pragma unroll
            for (int i = 0; i < 2; ++i) {
                pa[i][0] = __builtin_amdgcn_mfma_f32_16x16x32_bf16(aq[i][kk], bk0, pa[i][0], 0, 0, 0);
                pa[i][1] = __builtin_amdgcn_mfma_f32_16x16x32_bf16(aq[i][kk], bk1, pa[i][1], 0, 0, 0);
            }
        }
#pragma unroll
        for (int i = 0; i < 2; ++i) {
#pragma unroll
            for (int r = 0; r < 4; ++r) {
                int rloc = i * 16 + lg * 4 + r;
                int row128 = wid * 32 + rloc;
                float m0 = M[(size_t)row128 * NCL + mb + lr];
                float m1 = M[(size_t)row128 * NCL + mb + 16 + lr];
                float p0 = pa[i][0][r] * m0;
                float p1 = pa[i][1][r] * m1;
                float ss = fabsf(p0) + fabsf(p1);
                ss += __shfl_xor(ss, 1); ss += __shfl_xor(ss, 2);
                ss += __shfl_xor(ss, 4); ss += __shfl_xor(ss, 8);
                if (lr == 0) sl[row128] += ss;
                Ps[wid][rloc * 32 + lr]      = f2bf(p0);
                Ps[wid][rloc * 32 + 16 + lr] = f2bf(p1);
            }
        }
        __syncthreads();

        short8 ap[2];
#pragma unroll
        for (int i = 0; i < 2; ++i)
            ap[i] = *(const short8*)(Ps[wid] + (i * 16 + lr) * 32 + lg * 8);
#pragma unroll
        for (int n = 0; n < 8; ++n) {
            short8 bv8 = *(const short8*)(Vs + (n * 16 + lr) * 32 + lg * 8);
#pragma unroll
            for (int i = 0; i < 2; ++i)
                acc[i][n] = __builtin_amdgcn_mfma_f32_16x16x32_bf16(ap[i], bv8, acc[i][n], 0, 0, 0);
        }
        __syncthreads();
    }

    float* OR = iraw + ((size_t)bnh * NCL + (size_t)qt * 128) * NDK;
#pragma unroll
    for (int i = 0; i < 2; ++i)
#pragma unroll
        for (int n = 0; n < 8; ++n)
#pragma unroll
            for (int r = 0; r < 4; ++r) {
                int row = wid * 32 + i * 16 + lg * 4 + r;
                int col = n * 16 + lr;
                OR[(size_t)row * NDK + col] = acc[i][n][r];
            }
    __syncthreads();
    if (tid < 128) iscale[(size_t)bnh * NCL + qt * 128 + tid] = fmaxf(1.f, sl[tid]);
}

// ---------------------------------------------------------------------------
// kv_i[k][d] = sum_l krw[l][k] * v[l][d]
// ---------------------------------------------------------------------------
__global__ __launch_bounds__(256) void k_kv(
    const u16* __restrict__ krwT, const u16* __restrict__ vT, float* __restrict__ kvi)
{
    __shared__ __align__(16) u16 As[128 * 64];
    __shared__ __align__(16) u16 Bs[128 * 64];
    f32x4 acc[4][4];
#pragma unroll
    for (int m = 0; m < 4; ++m)
#pragma unroll
        for (int n = 0; n < 4; ++n) acc[m][n] = (f32x4){0.f, 0.f, 0.f, 0.f};

    int bnh = blockIdx.x;
    gemm_bt_core(krwT + (size_t)bnh * NDK * NCL, vT + (size_t)bnh * NDK * NCL,
                 NCL, NCL, NCL, As, Bs, acc);

    int tid = threadIdx.x, lane = tid & 63, lr = lane & 15, lg = lane >> 4, wid = tid >> 6;
    int wr = (wid >> 1) * 64, wc = (wid & 1) * 64;
    float* O = kvi + (size_t)bnh * NDK * NDK;
#pragma unroll
    for (int m = 0; m < 4; ++m)
#pragma unroll
        for (int n = 0; n < 4; ++n)
#pragma unroll
            for (int r = 0; r < 4; ++r) {
                int row = wr + m * 16 + lg * 4 + r;
                int col = wc + n * 16 + lr;
                O[(size_t)row * NDK + col] = acc[m][n][r];
            }
}

// ---------------------------------------------------------------------------
// Recurrent scan over chunks (unchanged)
// ---------------------------------------------------------------------------
__global__ __launch_bounds__(256) void k_scan(
    const float* __restrict__ kvi, const float* __restrict__ cdec,
    u16* __restrict__ kvrT, float* __restrict__ csc)
{
    int bh = blockIdx.x;
    int b = bh >> 4, h = bh & 15;
    float cd = cdec[h];
    int tid = threadIdx.x;
    int col = tid & 127;
    int r0 = (tid >> 7) * 64;
    float st[64];
#pragma unroll
    for (int i = 0; i < 64; ++i) st[i] = 0.f;
    float scale = 1.f;
    __shared__ float cs[128];
    __shared__ float scsh;

    for (int n = 0; n < NNC; ++n) {
        size_t idx = (size_t)((b * NNC + n) * NH + h);
        size_t kb = idx * (NDK * NDK);
        float inv = 1.f / scale;
#pragma unroll
        for (int i = 0; i < 64; ++i)
            kvrT[kb + (size_t)col * NDK + r0 + i] = f2bf(st[i] * inv);
        if (tid == 0) csc[idx] = scale;

        const float* KV = kvi + kb;
        float colsum = 0.f;
#pragma unroll
        for (int i = 0; i < 64; ++i) {
            float xv = st[i] * cd + KV[(size_t)(r0 + i) * NDK + col];
            st[i] = xv;
            colsum += fabsf(xv);
        }
        __syncthreads();
        if (tid < 128) cs[tid] = 0.f;
        __syncthreads();
        atomicAdd(&cs[col], colsum);
        __syncthreads();
        if (tid == 0) {
            float mx = cs[0];
            for (int i = 1; i < 128; ++i) mx = fmaxf(mx, cs[i]);
            scsh = fmaxf(1.f, mx);
        }
        __syncthreads();
        scale = scsh;
    }
}

// ---------------------------------------------------------------------------
// Combine (unchanged)
// ---------------------------------------------------------------------------
__global__ __launch_bounds__(256) void k_combine(
    const u16* __restrict__ qr, const u16* __restrict__ kvrT,
    const float* __restrict__ iraw, const float* __restrict__ iscale,
    const float* __restrict__ cscale, const float* __restrict__ idecay,
    const u16* __restrict__ glin, u16* __restrict__ y)
{
    __shared__ __align__(16) u16 As[128 * 64];
    __shared__ __align__(16) u16 Bs[128 * 64];
    __shared__ float ssum[128];
    __shared__ float ssq[128];
    f32x4 acc[4][4];
#pragma unroll
    for (int m = 0; m < 4; ++m)
#pragma unroll
        for (int n = 0; n < 4; ++n) acc[m][n] = (f32x4){0.f, 0.f, 0.f, 0.f};

    int qt = blockIdx.x, bnh = blockIdx.y;
    int b = bnh >> 7, cn = (bnh >> 4) & 7, h = bnh & 15;
    gemm_bt_core(qr + (size_t)bnh * NCL * NDK + (size_t)qt * 128 * NDK,
                 kvrT + (size_t)bnh * NDK * NDK, NDK, NDK, NDK, As, Bs, acc);

    int tid = threadIdx.x, lane = tid & 63, lr = lane & 15, lg = lane >> 4, wid = tid >> 6;
    int wr = (wid >> 1) * 64, wc = (wid & 1) * 64;
    if (tid < 128) { ssum[tid] = 0.f; ssq[tid] = 0.f; }
    __syncthreads();
    float csv = cscale[bnh];

#pragma unroll
    for (int m = 0; m < 4; ++m) {
#pragma unroll
        for (int r = 0; r < 4; ++r) {
            int rloc = wr + m * 16 + lg * 4 + r;
            int l = qt * 128 + rloc;
            float isc = iscale[(size_t)bnh * NCL + l];
            float all = fmaxf(isc, csv);
            float c1 = 1.f / all;
            float c2 = (csv / all) * idecay[h * NCL + l];
            const float* ir = iraw + ((size_t)bnh * NCL + l) * NDK;
            float lsum = 0.f, lsq = 0.f;
#pragma unroll
            for (int n = 0; n < 4; ++n) {
                int col = wc + n * 16 + lr;
                float v = ir[col] * c1 + acc[m][n][r] * c2;
                acc[m][n][r] = v;
                lsum += v; lsq += v * v;
            }
            lsum += __shfl_xor(lsum, 1); lsum += __shfl_xor(lsum, 2);
            lsum += __shfl_xor(lsum, 4); lsum += __shfl_xor(lsum, 8);
            lsq  += __shfl_xor(lsq, 1);  lsq  += __shfl_xor(lsq, 2);
            lsq  += __shfl_xor(lsq, 4);  lsq  += __shfl_xor(lsq, 8);
            if (lr == 0) { atomicAdd(&ssum[rloc], lsum); atomicAdd(&ssq[rloc], lsq); }
        }
    }
    __syncthreads();
#pragma unroll
    for (int m = 0; m < 4; ++m) {
#pragma unroll
        for (int r = 0; r < 4; ++r) {
            int rloc = wr + m * 16 + lg * 4 + r;
            int l = qt * 128 + rloc;
            float mu = ssum[rloc] * (1.f / 128.f);
            float var = ssq[rloc] * (1.f / 128.f) - mu * mu;
            float rstd = rsqrtf(fmaxf(var, 0.f) + 1e-6f);
            int t = cn * NCL + l;
            size_t obase = ((size_t)(b * NT + t)) * ND + (size_t)h * NDK;
#pragma unroll
            for (int n = 0; n < 4; ++n) {
                int col = wc + n * 16 + lr;
                float gv = bf2f(glin[obase + col]);
                float sg = gv / (1.f + expf(-gv));
                float ov = (acc[m][n][r] - mu) * rstd * sg;
                y[obase + col] = f2bf(ov);
            }
        }
    }
}

// ---------------------------------------------------------------------------
extern "C" void kernel_launch(void* const* d_in, const int* in_sizes, int n_in,
                              void* d_out, int out_size, void* d_ws, size_t ws_size,
                              hipStream_t stream)
{
    const float* x    = (const float*)d_in[0];
    const float* sinp = (const float*)d_in[1];
    const float* cosp = (const float*)d_in[2];
    const float* mask = (const float*)d_in[3];
    const float* cdec = (const float*)d_in[4];
    const float* idec = (const float*)d_in[5];
    const float* wq   = (const float*)d_in[6];
    const float* bq   = (const float*)d_in[7];
    const float* wk   = (const float*)d_in[8];
    const float* bk   = (const float*)d_in[9];
    const float* wv   = (const float*)d_in[10];
    const float* bv   = (const float*)d_in[11];
    const float* wg   = (const float*)d_in[12];
    const float* bg   = (const float*)d_in[13];
    const float* wo   = (const float*)d_in[14];
    const float* bo   = (const float*)d_in[15];
    float* out = (float*)d_out;

    // Workspace layout (~248 MB), lifetime-based aliasing (see round-2 notes)
    char* ws = (char*)d_ws;
    u16*   XB   = (u16*)(ws + 0);
    u16*   WB   = (u16*)(ws + 33554432);
    u16*   WOB  = (u16*)(ws + 67108864);
    u16*   QR   = (u16*)(ws + 75497472);
    u16*   KR   = (u16*)(ws + 109051904);
    u16*   KRWT = (u16*)(ws + 142606336);
    u16*   VT   = (u16*)(ws + 176160768);
    u16*   GLIN = (u16*)(ws + 209715200);
    float* KVI  = (float*)(ws + 243269632);
    float* CSC  = (float*)(ws + 260046848);
    float* IRAW = (float*)(ws + 0);           // alias XB+WB (dead after gemm1)
    u16*   Y    = KR;                         // alias KR (dead after inner)
    u16*   KVRT = KRWT;                       // alias KRWT (dead after kv)
    float* ISC  = (float*)(ws + 243269632);   // alias KVI (dead after scan)

    k_f2bf<<<2048, 256, 0, stream>>>(x, XB, 4194304);
    k_f2bf<<<1024, 256, 0, stream>>>(wq, WB,            1048576);
    k_f2bf<<<1024, 256, 0, stream>>>(wk, WB + 4194304,  1048576);
    k_f2bf<<<1024, 256, 0, stream>>>(wv, WB + 8388608,  1048576);
    k_f2bf<<<1024, 256, 0, stream>>>(wg, WB + 12582912, 1048576);
    k_f2bf<<<1024, 256, 0, stream>>>(wo, WOB,           1048576);

    k_gemm1<<<1024, 512, 0, stream>>>(XB, WB, bq, bk, bv, bg, sinp, cosp, mask,
                                      QR, KR, KRWT, VT, GLIN);
    k_kv<<<256, 256, 0, stream>>>(KRWT, VT, KVI);
    k_scan<<<32, 256, 0, stream>>>(KVI, cdec, KVRT, CSC);
    k_inner<<<dim3(4, 256), 256, 0, stream>>>(QR, KR, VT, mask, IRAW, ISC);
    k_combine<<<dim3(4, 256), 256, 0, stream>>>(QR, KVRT, IRAW, ISC, CSC, idec, GLIN, Y);
    k_gemm2<<<256, 512, 0, stream>>>(Y, WOB, bo, out);
}

// Round 7
// 943.554 us; speedup vs baseline: 1.2867x; 1.2867x over previous
//
#include <hip/hip_runtime.h>
#include <hip/hip_bf16.h>
#include <math.h>

// Problem constants
#define NB   2
#define NT   4096
#define ND   2048
#define NH   16
#define NDK  128
#define NCL  512
#define NNC  8
#define NTOK 8192
#define SCALING 0.08838834764831845f  // 128^-0.5

typedef unsigned short u16;
typedef short short8 __attribute__((ext_vector_type(8)));
typedef unsigned short ushort8 __attribute__((ext_vector_type(8)));
typedef float f32x4 __attribute__((ext_vector_type(4)));
typedef float float4v __attribute__((ext_vector_type(4)));
typedef short short4v __attribute__((ext_vector_type(4)));

__device__ __forceinline__ float bf2f(u16 u) {
    union { unsigned int i; float f; } v; v.i = ((unsigned int)u) << 16; return v.f;
}
__device__ __forceinline__ u16 f2bf(float f) {
    union { float f; unsigned int i; } v; v.f = f;
    unsigned int r = v.i + 0x7FFFu + ((v.i >> 16) & 1u);
    return (u16)(r >> 16);
}

// async global->LDS, 16B per lane (used only by the 128^2 core / k_inner).
__device__ __forceinline__ void gload16(const void* g, void* l) {
    __builtin_amdgcn_global_load_lds(
        (const __attribute__((address_space(1))) unsigned int*)g,
        (__attribute__((address_space(3))) unsigned int*)l, 16, 0, 0);
}

#define MFMA16(acc_, a_, b_) acc_ = __builtin_amdgcn_mfma_f32_16x16x32_bf16(a_, b_, acc_, 0, 0, 0)
#define SBAR  asm volatile("s_barrier" ::: "memory")

// ===========================================================================
// 256x256-tile 8-phase GEMM core, REGISTER-STAGED (T14), spill-proof:
//   C(256x256) = A(256xK) * B(256xK)^T, A/B row-major bf16, same ld.
//   512 threads = 8 waves (2 M x 4 N), per-wave 128x64 output, acc[8][4].
//   LDS: 4 distinct arrays A0/A1/B0/B1 (32 KB each). BK=64.
//   Staging: p0 issues 8 global_load_dwordx4 -> named regs (tile G+1);
//   p2 ds_writes A(G+1)->AWr; p3 ds_writes B(G+1)->BWr + lgkmcnt(0).
//   AWr/BWr are never read during tile G -> trivially WAR-safe; writes are
//   drained (lgkmcnt 0) two barriers before G+1's first read.
//   Register economy (per-wave cap 256 incl. AGPR acc=128): B-fragments are
//   PHASE-LOCAL (reloaded at p2/p3), staging addrs are one per-thread base +
//   uniform deltas, staging regs are named scalars. ~243 total regs.
//   T2: XOR swizzle on global source col + LDS read col (stores linear).
//   T5: setprio around MFMA clusters. No asm vmcnt (compiler's per-register
//   scoreboard is precise for reg-staged loads).
// ===========================================================================

__device__ __forceinline__ void tile4(
    int G, int nkt,
    const u16* Aop, const u16* Bop, size_t ld64,   // ld64 = 64*ld (elems)
    size_t goff0, int lwr,                          // per-thread bases
    int arow, int brow, int uc0, int uc1,
    u16* ARd, u16* BRd, u16* AWr, u16* BWr,
    f32x4 acc[8][4])
{
    short8 a[4][2], b[2][2];
    int4 ra0, ra1, ra2, ra3, rb0, rb1, rb2, rb3;
    const bool pf = (G + 1 < nkt);

    // ---- p0: issue global loads (tile G+1); read a(m0) + b=bA(n0)
    if (pf) {
        const u16* Ag = Aop + (size_t)(G + 1) * 64 + goff0;
        const u16* Bg = Bop + (size_t)(G + 1) * 64 + goff0;
        ra0 = *(const int4*)(Ag);
        ra1 = *(const int4*)(Ag + ld64);
        ra2 = *(const int4*)(Ag + 2 * ld64);
        ra3 = *(const int4*)(Ag + 3 * ld64);
        rb0 = *(const int4*)(Bg);
        rb1 = *(const int4*)(Bg + ld64);
        rb2 = *(const int4*)(Bg + 2 * ld64);
        rb3 = *(const int4*)(Bg + 3 * ld64);
    }
#pragma unroll
    for (int mf = 0; mf < 4; ++mf) {
        a[mf][0] = *(const short8*)(ARd + (size_t)(arow + mf * 16) * 64 + uc0);
        a[mf][1] = *(const short8*)(ARd + (size_t)(arow + mf * 16) * 64 + uc1);
    }
#pragma unroll
    for (int nf = 0; nf < 2; ++nf) {
        b[nf][0] = *(const short8*)(BRd + (size_t)(brow + nf * 16) * 64 + uc0);
        b[nf][1] = *(const short8*)(BRd + (size_t)(brow + nf * 16) * 64 + uc1);
    }
    SBAR;
    __builtin_amdgcn_s_setprio(1);
#pragma unroll
    for (int mf = 0; mf < 4; ++mf)
#pragma unroll
        for (int nf = 0; nf < 2; ++nf) {
            MFMA16(acc[mf][nf], a[mf][0], b[nf][0]);
            MFMA16(acc[mf][nf], a[mf][1], b[nf][1]);
        }
    __builtin_amdgcn_s_setprio(0);
    SBAR;

    // ---- p1: read b=bB(n1)
#pragma unroll
    for (int nf = 0; nf < 2; ++nf) {
        b[nf][0] = *(const short8*)(BRd + (size_t)(brow + 32 + nf * 16) * 64 + uc0);
        b[nf][1] = *(const short8*)(BRd + (size_t)(brow + 32 + nf * 16) * 64 + uc1);
    }
    SBAR;
    __builtin_amdgcn_s_setprio(1);
#pragma unroll
    for (int mf = 0; mf < 4; ++mf)
#pragma unroll
        for (int nf = 0; nf < 2; ++nf) {
            MFMA16(acc[mf][2 + nf], a[mf][0], b[nf][0]);
            MFMA16(acc[mf][2 + nf], a[mf][1], b[nf][1]);
        }
    __builtin_amdgcn_s_setprio(0);
    SBAR;

    // ---- p2: read a(m1); reload b=bB; ds_write A(G+1) -> AWr (unread this tile)
#pragma unroll
    for (int mf = 0; mf < 4; ++mf) {
        a[mf][0] = *(const short8*)(ARd + (size_t)(arow + 64 + mf * 16) * 64 + uc0);
        a[mf][1] = *(const short8*)(ARd + (size_t)(arow + 64 + mf * 16) * 64 + uc1);
    }
#pragma unroll
    for (int nf = 0; nf < 2; ++nf) {
        b[nf][0] = *(const short8*)(BRd + (size_t)(brow + 32 + nf * 16) * 64 + uc0);
        b[nf][1] = *(const short8*)(BRd + (size_t)(brow + 32 + nf * 16) * 64 + uc1);
    }
    if (pf) {
        *(int4*)((char*)AWr + lwr)         = ra0;
        *(int4*)((char*)AWr + lwr + 8192)  = ra1;
        *(int4*)((char*)AWr + lwr + 16384) = ra2;
        *(int4*)((char*)AWr + lwr + 24576) = ra3;
    }
    SBAR;
    __builtin_amdgcn_s_setprio(1);
#pragma unroll
    for (int mf = 0; mf < 4; ++mf)
#pragma unroll
        for (int nf = 0; nf < 2; ++nf) {
            MFMA16(acc[4 + mf][2 + nf], a[mf][0], b[nf][0]);
            MFMA16(acc[4 + mf][2 + nf], a[mf][1], b[nf][1]);
        }
    __builtin_amdgcn_s_setprio(0);
    SBAR;

    // ---- p3: reload b=bA; ds_write B(G+1) -> BWr; drain LDS writes
#pragma unroll
    for (int nf = 0; nf < 2; ++nf) {
        b[nf][0] = *(const short8*)(BRd + (size_t)(brow + nf * 16) * 64 + uc0);
        b[nf][1] = *(const short8*)(BRd + (size_t)(brow + nf * 16) * 64 + uc1);
    }
    if (pf) {
        *(int4*)((char*)BWr + lwr)         = rb0;
        *(int4*)((char*)BWr + lwr + 8192)  = rb1;
        *(int4*)((char*)BWr + lwr + 16384) = rb2;
        *(int4*)((char*)BWr + lwr + 24576) = rb3;
        asm volatile("s_waitcnt lgkmcnt(0)" ::: "memory");
    }
    SBAR;
    __builtin_amdgcn_s_setprio(1);
#pragma unroll
    for (int mf = 0; mf < 4; ++mf)
#pragma unroll
        for (int nf = 0; nf < 2; ++nf) {
            MFMA16(acc[4 + mf][nf], a[mf][0], b[nf][0]);
            MFMA16(acc[4 + mf][nf], a[mf][1], b[nf][1]);
        }
    __builtin_amdgcn_s_setprio(0);
    SBAR;
}

__device__ __forceinline__ void gemm256_core(
    const u16* Aop, const u16* Bop,
    int ld, int nkt,
    u16* A0, u16* A1, u16* B0, u16* B1, f32x4 acc[8][4])
{
    const int tid  = threadIdx.x;
    const int lane = tid & 63;
    const int lr   = lane & 15;
    const int lg   = lane >> 4;
    const int wid  = tid >> 6;
    const int wm   = wid >> 2;        // 0..1
    const int wn   = wid & 3;         // 0..3

    const int swz  = lr & 7;
    const int uc0  = ((0 * 4 + lg) ^ swz) * 8;   // kk=0 read unit (elems)
    const int uc1  = ((1 * 4 + lg) ^ swz) * 8;   // kk=1
    const int arow = wm * 128 + lr;
    const int brow = wn * 64 + lr;

    // per-thread staging base: chunk c=tid -> row=tid>>3, unit u=tid&7,
    // swizzled col (u^(row&7))*8; higher chunks are uniform +64*ld deltas.
    const int rw0 = tid >> 3, un0 = tid & 7;
    const size_t goff0 = (size_t)rw0 * ld + ((un0 ^ (rw0 & 7)) * 8);
    const size_t ld64 = (size_t)64 * ld;
    const int lwr = tid * 16;

    // prologue: tile 0 -> A0/B0 via regs
    {
        const u16* Ag = Aop + goff0;
        const u16* Bg = Bop + goff0;
        int4 t0 = *(const int4*)(Ag);
        int4 t1 = *(const int4*)(Ag + ld64);
        int4 t2 = *(const int4*)(Ag + 2 * ld64);
        int4 t3 = *(const int4*)(Ag + 3 * ld64);
        int4 u0 = *(const int4*)(Bg);
        int4 u1 = *(const int4*)(Bg + ld64);
        int4 u2 = *(const int4*)(Bg + 2 * ld64);
        int4 u3 = *(const int4*)(Bg + 3 * ld64);
        *(int4*)((char*)A0 + lwr)         = t0;
        *(int4*)((char*)A0 + lwr + 8192)  = t1;
        *(int4*)((char*)A0 + lwr + 16384) = t2;
        *(int4*)((char*)A0 + lwr + 24576) = t3;
        *(int4*)((char*)B0 + lwr)         = u0;
        *(int4*)((char*)B0 + lwr + 8192)  = u1;
        *(int4*)((char*)B0 + lwr + 16384) = u2;
        *(int4*)((char*)B0 + lwr + 24576) = u3;
        asm volatile("s_waitcnt lgkmcnt(0)" ::: "memory");
        SBAR;
    }

    for (int G = 0; G < nkt; G += 2) {
        tile4(G,     nkt, Aop, Bop, ld64, goff0, lwr, arow, brow, uc0, uc1,
              A0, B0, A1, B1, acc);
        tile4(G + 1, nkt, Aop, Bop, ld64, goff0, lwr, arow, brow, uc0, uc1,
              A1, B1, A0, B0, acc);
    }
}

// ---------------------------------------------------------------------------
// Old 128x128 core (kept for the small GEMMs: kv, combine)
// ---------------------------------------------------------------------------
__device__ __forceinline__ void gemm_bt_core(
    const u16* __restrict__ A, const u16* __restrict__ Bm,
    int lda, int ldb, int K, u16* As, u16* Bs, f32x4 acc[4][4])
{
    const int tid  = threadIdx.x;
    const int lane = tid & 63;
    const int lr   = lane & 15;
    const int lg   = lane >> 4;
    const int wid  = tid >> 6;
    const int wr   = (wid >> 1) * 64;
    const int wc   = (wid & 1) * 64;
    for (int kt = 0; kt < K; kt += 64) {
#pragma unroll
        for (int i = 0; i < 4; ++i) {
            int c = tid + i * 256;
            int row = c >> 3, col = (c & 7) * 8;
            gload16(A  + (size_t)row * lda + kt + col, (char*)As + (size_t)c * 16);
            gload16(Bm + (size_t)row * ldb + kt + col, (char*)Bs + (size_t)c * 16);
        }
        __syncthreads();
#pragma unroll
        for (int kk = 0; kk < 2; ++kk) {
            short8 a[4], b[4];
#pragma unroll
            for (int m = 0; m < 4; ++m)
                a[m] = *(const short8*)(As + (wr + m * 16 + lr) * 64 + kk * 32 + lg * 8);
#pragma unroll
            for (int n = 0; n < 4; ++n)
                b[n] = *(const short8*)(Bs + (wc + n * 16 + lr) * 64 + kk * 32 + lg * 8);
#pragma unroll
            for (int m = 0; m < 4; ++m)
#pragma unroll
                for (int n = 0; n < 4; ++n)
                    acc[m][n] = __builtin_amdgcn_mfma_f32_16x16x32_bf16(a[m], b[n], acc[m][n], 0, 0, 0);
        }
        __syncthreads();
    }
}

// ---------------------------------------------------------------------------
// fp32 -> bf16 convert
// ---------------------------------------------------------------------------
__global__ __launch_bounds__(256) void k_f2bf(const float* __restrict__ src,
                                              u16* __restrict__ dst, int n4)
{
    int i = blockIdx.x * blockDim.x + threadIdx.x;
    int stride = gridDim.x * blockDim.x;
    for (int j = i; j < n4; j += stride) {
        float4v f = *(const float4v*)(src + (size_t)j * 4);
        short4v o;
        o.x = (short)f2bf(f.x); o.y = (short)f2bf(f.y);
        o.z = (short)f2bf(f.z); o.w = (short)f2bf(f.w);
        *(short4v*)(dst + (size_t)j * 4) = o;
    }
}

// ---------------------------------------------------------------------------
// GEMM1 (256^2 8-phase): [8192 x 2048] x [8192 x 2048]^T; epilogue fuses
// bias + rotary (q,k), k-scaling, decay-weighted transposed krwT, vT, g.
// ---------------------------------------------------------------------------
__global__ __launch_bounds__(512, 2) void k_gemm1(
    const u16* __restrict__ xb, const u16* __restrict__ wb,
    const float* __restrict__ bq, const float* __restrict__ bk,
    const float* __restrict__ bv, const float* __restrict__ bg,
    const float* __restrict__ sinp, const float* __restrict__ cosp,
    const float* __restrict__ maskp,
    u16* __restrict__ qro, u16* __restrict__ kro, u16* __restrict__ krwT,
    u16* __restrict__ vT, u16* __restrict__ glin)
{
    __shared__ __align__(16) u16 A0[256 * 64];
    __shared__ __align__(16) u16 A1[256 * 64];
    __shared__ __align__(16) u16 B0[256 * 64];
    __shared__ __align__(16) u16 B1[256 * 64];
    f32x4 acc[8][4];
#pragma unroll
    for (int m = 0; m < 8; ++m)
#pragma unroll
        for (int n = 0; n < 4; ++n) acc[m][n] = (f32x4){0.f, 0.f, 0.f, 0.f};

    // T1 bijective XCD swizzle: nwg=1024, 1024%8==0
    int bid = blockIdx.x;
    int swzb = (bid & 7) * 128 + (bid >> 3);
    int mt = swzb >> 5, nt = swzb & 31;          // 32 x 32 tiles of 256

    gemm256_core(xb + (size_t)mt * 256 * ND, wb + (size_t)nt * 256 * ND,
                 ND, ND / 64, A0, A1, B0, B1, acc);

    int tid = threadIdx.x, lane = tid & 63, lr = lane & 15, lg = lane >> 4, wid = tid >> 6;
    int wm = wid >> 2, wn = wid & 3;
    int which = nt >> 3;   // 0:q 1:k 2:v 3:g (uniform per block)

    if (which <= 1) {
        const float* bias = (which == 0) ? bq : bk;
#pragma unroll
        for (int mf = 0; mf < 8; ++mf) {
#pragma unroll
            for (int nf = 0; nf < 4; ++nf) {
#pragma unroll
                for (int r = 0; r < 4; ++r) {
                    int row = mt * 256 + wm * 128 + mf * 16 + lg * 4 + r;
                    int col = nt * 256 + wn * 64 + nf * 16 + lr;
                    int f = col & 2047, h = f >> 7, d = f & 127;
                    int b = row >> 12, t = row & 4095, cn = t >> 9, cl = t & 511;
                    float v = acc[mf][nf][r] + bias[f];
                    if (which == 1) v *= SCALING;
                    float sv = sinp[(size_t)t * NDK + d];
                    float cv = cosp[(size_t)t * NDK + d];
                    float vp = __shfl_xor(v, 1);          // partner feature (col^1)
                    float rot = (lr & 1) ? vp : -vp;      // rotate_every_two
                    float o = v * cv + rot * sv;
                    size_t chbase = (size_t)(b * NNC + cn) * NH + h;
                    if (which == 0) {
                        qro[(chbase * NCL + cl) * NDK + d] = f2bf(o);
                    } else {
                        kro[(chbase * NCL + cl) * NDK + d] = f2bf(o);
                        float w = maskp[((size_t)h * NCL + (NCL - 1)) * NCL + cl];
                        krwT[(chbase * NDK + d) * NCL + cl] = f2bf(o * w);
                    }
                }
            }
        }
    } else {
#pragma unroll
        for (int mf = 0; mf < 8; ++mf) {
#pragma unroll
            for (int nf = 0; nf < 4; ++nf) {
#pragma unroll
                for (int r = 0; r < 4; ++r) {
                    int row = mt * 256 + wm * 128 + mf * 16 + lg * 4 + r;
                    int col = nt * 256 + wn * 64 + nf * 16 + lr;
                    int f = col & 2047;
                    float v = acc[mf][nf][r];
                    if (which == 2) {
                        int h = f >> 7, d = f & 127;
                        int b = row >> 12, t = row & 4095, cn = t >> 9, cl = t & 511;
                        vT[(((size_t)(b * NNC + cn) * NH + h) * NDK + d) * NCL + cl] = f2bf(v + bv[f]);
                    } else {
                        glin[(size_t)row * ND + f] = f2bf(v + bg[f]);
                    }
                }
            }
        }
    }
}

// ---------------------------------------------------------------------------
// GEMM2 (256^2 8-phase): y[8192x2048] x wo[2048x2048]^T + bo -> fp32 out
// ---------------------------------------------------------------------------
__global__ __launch_bounds__(512, 2) void k_gemm2(
    const u16* __restrict__ y, const u16* __restrict__ wob,
    const float* __restrict__ bo, float* __restrict__ out)
{
    __shared__ __align__(16) u16 A0[256 * 64];
    __shared__ __align__(16) u16 A1[256 * 64];
    __shared__ __align__(16) u16 B0[256 * 64];
    __shared__ __align__(16) u16 B1[256 * 64];
    f32x4 acc[8][4];
#pragma unroll
    for (int m = 0; m < 8; ++m)
#pragma unroll
        for (int n = 0; n < 4; ++n) acc[m][n] = (f32x4){0.f, 0.f, 0.f, 0.f};

    // nwg = 256, 256%8==0
    int bid = blockIdx.x;
    int swzb = (bid & 7) * 32 + (bid >> 3);
    int mt = swzb >> 3, nt = swzb & 7;           // 32 x 8 tiles of 256

    gemm256_core(y + (size_t)mt * 256 * ND, wob + (size_t)nt * 256 * ND,
                 ND, ND / 64, A0, A1, B0, B1, acc);

    int tid = threadIdx.x, lane = tid & 63, lr = lane & 15, lg = lane >> 4, wid = tid >> 6;
    int wm = wid >> 2, wn = wid & 3;
#pragma unroll
    for (int mf = 0; mf < 8; ++mf)
#pragma unroll
        for (int nf = 0; nf < 4; ++nf)
#pragma unroll
            for (int r = 0; r < 4; ++r) {
                int row = mt * 256 + wm * 128 + mf * 16 + lg * 4 + r;
                int col = nt * 256 + wn * 64 + nf * 16 + lr;
                out[(size_t)row * ND + col] = acc[mf][nf][r] + bo[col];
            }
}

// ---------------------------------------------------------------------------
// Inner retention (unchanged): P = (Q K^T)*mask ; s=row|P|sum ; iraw = P @ V.
// ---------------------------------------------------------------------------
__global__ __launch_bounds__(256) void k_inner(
    const u16* __restrict__ qr, const u16* __restrict__ kr,
    const u16* __restrict__ vT, const float* __restrict__ mask,
    float* __restrict__ iraw, float* __restrict__ iscale)
{
    __shared__ __align__(16) u16 Qs[128 * 128];
    __shared__ __align__(16) u16 Ks[32 * 128];
    __shared__ __align__(16) u16 Vs[128 * 32];
    __shared__ __align__(16) u16 Ps[4][32 * 32];
    __shared__ float sl[128];

    int qt = blockIdx.x, bnh = blockIdx.y;
    int h = bnh & 15;
    const u16* Q = qr + (size_t)bnh * NCL * NDK + (size_t)qt * 128 * NDK;
    const u16* K = kr + (size_t)bnh * NCL * NDK;
    const u16* V = vT + (size_t)bnh * NDK * NCL;
    const float* M = mask + (size_t)h * NCL * NCL + (size_t)qt * 128 * NCL;

    int tid = threadIdx.x, lane = tid & 63, lr = lane & 15, lg = lane >> 4, wid = tid >> 6;
    if (tid < 128) sl[tid] = 0.f;
#pragma unroll
    for (int i = 0; i < 8; ++i) {
        int c = tid + i * 256;
        gload16(Q + (size_t)c * 8, (char*)Qs + (size_t)c * 16);
    }
    __syncthreads();

    short8 aq[2][4];
#pragma unroll
    for (int i = 0; i < 2; ++i)
#pragma unroll
        for (int kk = 0; kk < 4; ++kk)
            aq[i][kk] = *(const short8*)(Qs + (wid * 32 + i * 16 + lr) * 128 + kk * 32 + lg * 8);

    f32x4 acc[2][8];
#pragma unroll
    for (int i = 0; i < 2; ++i)
#pragma unroll
        for (int n = 0; n < 8; ++n) acc[i][n] = (f32x4){0.f, 0.f, 0.f, 0.f};

    int msteps = qt * 4 + 4;
    for (int ms = 0; ms < msteps; ++ms) {
        int mb = ms * 32;
#pragma unroll
        for (int i = 0; i < 2; ++i) {
            int c = tid + i * 256;
            int row = c >> 4, cc = (c & 15) * 8;
            gload16(K + (size_t)(mb + row) * NDK + cc, (char*)Ks + (size_t)c * 16);
        }
#pragma unroll
        for (int i = 0; i < 2; ++i) {
            int c = tid + i * 256;
            int row = c >> 2, cc = (c & 3) * 8;
            gload16(V + (size_t)row * NCL + mb + cc, (char*)Vs + (size_t)c * 16);
        }
        __syncthreads();

        f32x4 pa[2][2];
#pragma unroll
        for (int i = 0; i < 2; ++i) { pa[i][0] = (f32x4){0.f,0.f,0.f,0.f}; pa[i][1] = (f32x4){0.f,0.f,0.f,0.f}; }
#pragma unroll
        for (int kk = 0; kk < 4; ++kk) {
            short8 bk0 = *(const short8*)(Ks + (lr) * 128 + kk * 32 + lg * 8);
            short8 bk1 = *(const short8*)(Ks + (16 + lr) * 128 + kk * 32 + lg * 8);
#pragma unroll
            for (int i = 0; i < 2; ++i) {
                pa[i][0] = __builtin_amdgcn_mfma_f32_16x16x32_bf16(aq[i][kk], bk0, pa[i][0], 0, 0, 0);
                pa[i][1] = __builtin_amdgcn_mfma_f32_16x16x32_bf16(aq[i][kk], bk1, pa[i][1], 0, 0, 0);
            }
        }
#pragma unroll
        for (int i = 0; i < 2; ++i) {
#pragma unroll
            for (int r = 0; r < 4; ++r) {
                int rloc = i * 16 + lg * 4 + r;
                int row128 = wid * 32 + rloc;
                float m0 = M[(size_t)row128 * NCL + mb + lr];
                float m1 = M[(size_t)row128 * NCL + mb + 16 + lr];
                float p0 = pa[i][0][r] * m0;
                float p1 = pa[i][1][r] * m1;
                float ss = fabsf(p0) + fabsf(p1);
                ss += __shfl_xor(ss, 1); ss += __shfl_xor(ss, 2);
                ss += __shfl_xor(ss, 4); ss += __shfl_xor(ss, 8);
                if (lr == 0) sl[row128] += ss;
                Ps[wid][rloc * 32 + lr]      = f2bf(p0);
                Ps[wid][rloc * 32 + 16 + lr] = f2bf(p1);
            }
        }
        __syncthreads();

        short8 ap[2];
#pragma unroll
        for (int i = 0; i < 2; ++i)
            ap[i] = *(const short8*)(Ps[wid] + (i * 16 + lr) * 32 + lg * 8);
#pragma unroll
        for (int n = 0; n < 8; ++n) {
            short8 bv8 = *(const short8*)(Vs + (n * 16 + lr) * 32 + lg * 8);
#pragma unroll
            for (int i = 0; i < 2; ++i)
                acc[i][n] = __builtin_amdgcn_mfma_f32_16x16x32_bf16(ap[i], bv8, acc[i][n], 0, 0, 0);
        }
        __syncthreads();
    }

    float* OR = iraw + ((size_t)bnh * NCL + (size_t)qt * 128) * NDK;
#pragma unroll
    for (int i = 0; i < 2; ++i)
#pragma unroll
        for (int n = 0; n < 8; ++n)
#pragma unroll
            for (int r = 0; r < 4; ++r) {
                int row = wid * 32 + i * 16 + lg * 4 + r;
                int col = n * 16 + lr;
                OR[(size_t)row * NDK + col] = acc[i][n][r];
            }
    __syncthreads();
    if (tid < 128) iscale[(size_t)bnh * NCL + qt * 128 + tid] = fmaxf(1.f, sl[tid]);
}

// ---------------------------------------------------------------------------
// kv_i[k][d] = sum_l krw[l][k] * v[l][d]
// ---------------------------------------------------------------------------
__global__ __launch_bounds__(256) void k_kv(
    const u16* __restrict__ krwT, const u16* __restrict__ vT, float* __restrict__ kvi)
{
    __shared__ __align__(16) u16 As[128 * 64];
    __shared__ __align__(16) u16 Bs[128 * 64];
    f32x4 acc[4][4];
#pragma unroll
    for (int m = 0; m < 4; ++m)
#pragma unroll
        for (int n = 0; n < 4; ++n) acc[m][n] = (f32x4){0.f, 0.f, 0.f, 0.f};

    int bnh = blockIdx.x;
    gemm_bt_core(krwT + (size_t)bnh * NDK * NCL, vT + (size_t)bnh * NDK * NCL,
                 NCL, NCL, NCL, As, Bs, acc);

    int tid = threadIdx.x, lane = tid & 63, lr = lane & 15, lg = lane >> 4, wid = tid >> 6;
    int wr = (wid >> 1) * 64, wc = (wid & 1) * 64;
    float* O = kvi + (size_t)bnh * NDK * NDK;
#pragma unroll
    for (int m = 0; m < 4; ++m)
#pragma unroll
        for (int n = 0; n < 4; ++n)
#pragma unroll
            for (int r = 0; r < 4; ++r) {
                int row = wr + m * 16 + lg * 4 + r;
                int col = wc + n * 16 + lr;
                O[(size_t)row * NDK + col] = acc[m][n][r];
            }
}

// ---------------------------------------------------------------------------
// Recurrent scan over chunks (unchanged)
// ---------------------------------------------------------------------------
__global__ __launch_bounds__(256) void k_scan(
    const float* __restrict__ kvi, const float* __restrict__ cdec,
    u16* __restrict__ kvrT, float* __restrict__ csc)
{
    int bh = blockIdx.x;
    int b = bh >> 4, h = bh & 15;
    float cd = cdec[h];
    int tid = threadIdx.x;
    int col = tid & 127;
    int r0 = (tid >> 7) * 64;
    float st[64];
#pragma unroll
    for (int i = 0; i < 64; ++i) st[i] = 0.f;
    float scale = 1.f;
    __shared__ float cs[128];
    __shared__ float scsh;

    for (int n = 0; n < NNC; ++n) {
        size_t idx = (size_t)((b * NNC + n) * NH + h);
        size_t kb = idx * (NDK * NDK);
        float inv = 1.f / scale;
#pragma unroll
        for (int i = 0; i < 64; ++i)
            kvrT[kb + (size_t)col * NDK + r0 + i] = f2bf(st[i] * inv);
        if (tid == 0) csc[idx] = scale;

        const float* KV = kvi + kb;
        float colsum = 0.f;
#pragma unroll
        for (int i = 0; i < 64; ++i) {
            float xv = st[i] * cd + KV[(size_t)(r0 + i) * NDK + col];
            st[i] = xv;
            colsum += fabsf(xv);
        }
        __syncthreads();
        if (tid < 128) cs[tid] = 0.f;
        __syncthreads();
        atomicAdd(&cs[col], colsum);
        __syncthreads();
        if (tid == 0) {
            float mx = cs[0];
            for (int i = 1; i < 128; ++i) mx = fmaxf(mx, cs[i]);
            scsh = fmaxf(1.f, mx);
        }
        __syncthreads();
        scale = scsh;
    }
}

// ---------------------------------------------------------------------------
// Combine (unchanged)
// ---------------------------------------------------------------------------
__global__ __launch_bounds__(256) void k_combine(
    const u16* __restrict__ qr, const u16* __restrict__ kvrT,
    const float* __restrict__ iraw, const float* __restrict__ iscale,
    const float* __restrict__ cscale, const float* __restrict__ idecay,
    const u16* __restrict__ glin, u16* __restrict__ y)
{
    __shared__ __align__(16) u16 As[128 * 64];
    __shared__ __align__(16) u16 Bs[128 * 64];
    __shared__ float ssum[128];
    __shared__ float ssq[128];
    f32x4 acc[4][4];
#pragma unroll
    for (int m = 0; m < 4; ++m)
#pragma unroll
        for (int n = 0; n < 4; ++n) acc[m][n] = (f32x4){0.f, 0.f, 0.f, 0.f};

    int qt = blockIdx.x, bnh = blockIdx.y;
    int b = bnh >> 7, cn = (bnh >> 4) & 7, h = bnh & 15;
    gemm_bt_core(qr + (size_t)bnh * NCL * NDK + (size_t)qt * 128 * NDK,
                 kvrT + (size_t)bnh * NDK * NDK, NDK, NDK, NDK, As, Bs, acc);

    int tid = threadIdx.x, lane = tid & 63, lr = lane & 15, lg = lane >> 4, wid = tid >> 6;
    int wr = (wid >> 1) * 64, wc = (wid & 1) * 64;
    if (tid < 128) { ssum[tid] = 0.f; ssq[tid] = 0.f; }
    __syncthreads();
    float csv = cscale[bnh];

#pragma unroll
    for (int m = 0; m < 4; ++m) {
#pragma unroll
        for (int r = 0; r < 4; ++r) {
            int rloc = wr + m * 16 + lg * 4 + r;
            int l = qt * 128 + rloc;
            float isc = iscale[(size_t)bnh * NCL + l];
            float all = fmaxf(isc, csv);
            float c1 = 1.f / all;
            float c2 = (csv / all) * idecay[h * NCL + l];
            const float* ir = iraw + ((size_t)bnh * NCL + l) * NDK;
            float lsum = 0.f, lsq = 0.f;
#pragma unroll
            for (int n = 0; n < 4; ++n) {
                int col = wc + n * 16 + lr;
                float v = ir[col] * c1 + acc[m][n][r] * c2;
                acc[m][n][r] = v;
                lsum += v; lsq += v * v;
            }
            lsum += __shfl_xor(lsum, 1); lsum += __shfl_xor(lsum, 2);
            lsum += __shfl_xor(lsum, 4); lsum += __shfl_xor(lsum, 8);
            lsq  += __shfl_xor(lsq, 1);  lsq  += __shfl_xor(lsq, 2);
            lsq  += __shfl_xor(lsq, 4);  lsq  += __shfl_xor(lsq, 8);
            if (lr == 0) { atomicAdd(&ssum[rloc], lsum); atomicAdd(&ssq[rloc], lsq); }
        }
    }
    __syncthreads();
#pragma unroll
    for (int m = 0; m < 4; ++m) {
#pragma unroll
        for (int r = 0; r < 4; ++r) {
            int rloc = wr + m * 16 + lg * 4 + r;
            int l = qt * 128 + rloc;
            float mu = ssum[rloc] * (1.f / 128.f);
            float var = ssq[rloc] * (1.f / 128.f) - mu * mu;
            float rstd = rsqrtf(fmaxf(var, 0.f) + 1e-6f);
            int t = cn * NCL + l;
            size_t obase = ((size_t)(b * NT + t)) * ND + (size_t)h * NDK;
#pragma unroll
            for (int n = 0; n < 4; ++n) {
                int col = wc + n * 16 + lr;
                float gv = bf2f(glin[obase + col]);
                float sg = gv / (1.f + expf(-gv));
                float ov = (acc[m][n][r] - mu) * rstd * sg;
                y[obase + col] = f2bf(ov);
            }
        }
    }
}

// ---------------------------------------------------------------------------
extern "C" void kernel_launch(void* const* d_in, const int* in_sizes, int n_in,
                              void* d_out, int out_size, void* d_ws, size_t ws_size,
                              hipStream_t stream)
{
    const float* x    = (const float*)d_in[0];
    const float* sinp = (const float*)d_in[1];
    const float* cosp = (const float*)d_in[2];
    const float* mask = (const float*)d_in[3];
    const float* cdec = (const float*)d_in[4];
    const float* idec = (const float*)d_in[5];
    const float* wq   = (const float*)d_in[6];
    const float* bq   = (const float*)d_in[7];
    const float* wk   = (const float*)d_in[8];
    const float* bk   = (const float*)d_in[9];
    const float* wv   = (const float*)d_in[10];
    const float* bv   = (const float*)d_in[11];
    const float* wg   = (const float*)d_in[12];
    const float* bg   = (const float*)d_in[13];
    const float* wo   = (const float*)d_in[14];
    const float* bo   = (const float*)d_in[15];
    float* out = (float*)d_out;

    // Workspace layout (~248 MB), lifetime-based aliasing (see round-2 notes)
    char* ws = (char*)d_ws;
    u16*   XB   = (u16*)(ws + 0);
    u16*   WB   = (u16*)(ws + 33554432);
    u16*   WOB  = (u16*)(ws + 67108864);
    u16*   QR   = (u16*)(ws + 75497472);
    u16*   KR   = (u16*)(ws + 109051904);
    u16*   KRWT = (u16*)(ws + 142606336);
    u16*   VT   = (u16*)(ws + 176160768);
    u16*   GLIN = (u16*)(ws + 209715200);
    float* KVI  = (float*)(ws + 243269632);
    float* CSC  = (float*)(ws + 260046848);
    float* IRAW = (float*)(ws + 0);           // alias XB+WB (dead after gemm1)
    u16*   Y    = KR;                         // alias KR (dead after inner)
    u16*   KVRT = KRWT;                       // alias KRWT (dead after kv)
    float* ISC  = (float*)(ws + 243269632);   // alias KVI (dead after scan)

    k_f2bf<<<2048, 256, 0, stream>>>(x, XB, 4194304);
    k_f2bf<<<1024, 256, 0, stream>>>(wq, WB,            1048576);
    k_f2bf<<<1024, 256, 0, stream>>>(wk, WB + 4194304,  1048576);
    k_f2bf<<<1024, 256, 0, stream>>>(wv, WB + 8388608,  1048576);
    k_f2bf<<<1024, 256, 0, stream>>>(wg, WB + 12582912, 1048576);
    k_f2bf<<<1024, 256, 0, stream>>>(wo, WOB,           1048576);

    k_gemm1<<<1024, 512, 0, stream>>>(XB, WB, bq, bk, bv, bg, sinp, cosp, mask,
                                      QR, KR, KRWT, VT, GLIN);
    k_kv<<<256, 256, 0, stream>>>(KRWT, VT, KVI);
    k_scan<<<32, 256, 0, stream>>>(KVI, cdec, KVRT, CSC);
    k_inner<<<dim3(4, 256), 256, 0, stream>>>(QR, KR, VT, mask, IRAW, ISC);
    k_combine<<<dim3(4, 256), 256, 0, stream>>>(QR, KVRT, IRAW, ISC, CSC, idec, GLIN, Y);
    k_gemm2<<<256, 512, 0, stream>>>(Y, WOB, bo, out);
}

// Round 8
// 878.002 us; speedup vs baseline: 1.3828x; 1.0747x over previous
//
#include <hip/hip_runtime.h>
#include <hip/hip_bf16.h>
#include <math.h>

// Problem constants
#define NB   2
#define NT   4096
#define ND   2048
#define NH   16
#define NDK  128
#define NCL  512
#define NNC  8
#define NTOK 8192
#define SCALING 0.08838834764831845f  // 128^-0.5

typedef unsigned short u16;
typedef short short8 __attribute__((ext_vector_type(8)));
typedef unsigned short ushort8 __attribute__((ext_vector_type(8)));
typedef float f32x4 __attribute__((ext_vector_type(4)));
typedef float float4v __attribute__((ext_vector_type(4)));
typedef short short4v __attribute__((ext_vector_type(4)));

__device__ __forceinline__ float bf2f(u16 u) {
    union { unsigned int i; float f; } v; v.i = ((unsigned int)u) << 16; return v.f;
}
__device__ __forceinline__ u16 f2bf(float f) {
    union { float f; unsigned int i; } v; v.f = f;
    unsigned int r = v.i + 0x7FFFu + ((v.i >> 16) & 1u);
    return (u16)(r >> 16);
}

// async global->LDS, 16B per lane. LDS dest linear: wave base + lane*16.
__device__ __forceinline__ void gload16(const void* g, void* l) {
    __builtin_amdgcn_global_load_lds(
        (const __attribute__((address_space(1))) unsigned int*)g,
        (__attribute__((address_space(3))) unsigned int*)l, 16, 0, 0);
}

#define MFMA16(acc_, a_, b_) acc_ = __builtin_amdgcn_mfma_f32_16x16x32_bf16(a_, b_, acc_, 0, 0, 0)
#define SBAR  asm volatile("s_barrier" ::: "memory")

// ===========================================================================
// 256x256-tile GEMM core, BARRIER-MINIMAL (1 sync per K-tile):
//   C(256x256) = A(256xK) * B(256xK)^T, A/B row-major bf16, same ld.
//   512 threads = 8 waves (2 M x 4 N), per-wave 128x64 output, acc[8][4].
//   LDS: 4 distinct arrays A0/A1/B0/B1 (32 KB each). BK=64.
//   Staging: ALL of tile G+1 staged at tile-G start via global_load_lds into
//   the NON-READ buffer pair (AWr/BWr). ds_reads(ARd/BRd) vs DMA-writes
//   (AWr/BWr) are provably-distinct LDS objects -> compiler inserts NO
//   intra-tile waits. No intra-tile barriers: within a tile there is zero
//   cross-wave LDS dependency (reads hit the stable pair, writes the other).
//   Boundary per K-tile: s_waitcnt vmcnt(0) lgkmcnt(0); s_barrier.
//     - vmcnt(0): retires the 8 stages issued ~2500 cyc earlier (cheap)
//     - lgkmcnt(0): drains this wave's ds_reads (WAR vs next tile's DMA)
//   Waves drift within a tile -> LDS-read latency overlaps other waves' MFMA.
//   T2: XOR swizzle on global source col + LDS read col (DMA dest linear).
//   T5: setprio around MFMA clusters.
// ===========================================================================

// stage one 128x64 half-tile: g = global base of this half's first row (incl. kt)
__device__ __forceinline__ void stage_half(const u16* __restrict__ g, int ld,
                                           u16* lds, int tid)
{
#pragma unroll
    for (int j = 0; j < 2; ++j) {
        int c = tid + j * 512;            // 0..1023 16B chunks
        int row = c >> 3, u = c & 7;
        gload16(g + (size_t)row * ld + ((u ^ (row & 7)) * 8), lds + (size_t)c * 8);
    }
}

__device__ __forceinline__ void tile_nb(
    int G, int nkt,
    const u16* Aop, const u16* Bop, int ld,
    int tid, int arow, int brow, int uc0, int uc1,
    u16* ARd, u16* BRd, u16* AWr, u16* BWr,
    f32x4 acc[8][4])
{
    // stage ALL of tile G+1 into the non-read pair (distinct LDS objects)
    if (G + 1 < nkt) {
        const u16* Ag = Aop + (size_t)(G + 1) * 64;
        const u16* Bg = Bop + (size_t)(G + 1) * 64;
        stage_half(Ag,                    ld, AWr,        tid);
        stage_half(Ag + (size_t)128 * ld, ld, AWr + 8192, tid);
        stage_half(Bg,                    ld, BWr,        tid);
        stage_half(Bg + (size_t)128 * ld, ld, BWr + 8192, tid);
    }

    short8 a[4][2], bA[2][2], bB[2][2];

    // group 0: (m0, n0)
#pragma unroll
    for (int mf = 0; mf < 4; ++mf) {
        a[mf][0] = *(const short8*)(ARd + (size_t)(arow + mf * 16) * 64 + uc0);
        a[mf][1] = *(const short8*)(ARd + (size_t)(arow + mf * 16) * 64 + uc1);
    }
#pragma unroll
    for (int nf = 0; nf < 2; ++nf) {
        bA[nf][0] = *(const short8*)(BRd + (size_t)(brow + nf * 16) * 64 + uc0);
        bA[nf][1] = *(const short8*)(BRd + (size_t)(brow + nf * 16) * 64 + uc1);
    }
    __builtin_amdgcn_s_setprio(1);
#pragma unroll
    for (int mf = 0; mf < 4; ++mf)
#pragma unroll
        for (int nf = 0; nf < 2; ++nf) {
            MFMA16(acc[mf][nf], a[mf][0], bA[nf][0]);
            MFMA16(acc[mf][nf], a[mf][1], bA[nf][1]);
        }
    __builtin_amdgcn_s_setprio(0);

    // group 1: (m0, n1)
#pragma unroll
    for (int nf = 0; nf < 2; ++nf) {
        bB[nf][0] = *(const short8*)(BRd + (size_t)(brow + 32 + nf * 16) * 64 + uc0);
        bB[nf][1] = *(const short8*)(BRd + (size_t)(brow + 32 + nf * 16) * 64 + uc1);
    }
    __builtin_amdgcn_s_setprio(1);
#pragma unroll
    for (int mf = 0; mf < 4; ++mf)
#pragma unroll
        for (int nf = 0; nf < 2; ++nf) {
            MFMA16(acc[mf][2 + nf], a[mf][0], bB[nf][0]);
            MFMA16(acc[mf][2 + nf], a[mf][1], bB[nf][1]);
        }
    __builtin_amdgcn_s_setprio(0);

    // group 2: (m1, n1)  (a overwritten with m1 fragments)
#pragma unroll
    for (int mf = 0; mf < 4; ++mf) {
        a[mf][0] = *(const short8*)(ARd + (size_t)(arow + 64 + mf * 16) * 64 + uc0);
        a[mf][1] = *(const short8*)(ARd + (size_t)(arow + 64 + mf * 16) * 64 + uc1);
    }
    __builtin_amdgcn_s_setprio(1);
#pragma unroll
    for (int mf = 0; mf < 4; ++mf)
#pragma unroll
        for (int nf = 0; nf < 2; ++nf) {
            MFMA16(acc[4 + mf][2 + nf], a[mf][0], bB[nf][0]);
            MFMA16(acc[4 + mf][2 + nf], a[mf][1], bB[nf][1]);
        }
    __builtin_amdgcn_s_setprio(0);

    // group 3: (m1, n0)  (bA still live from group 0)
    __builtin_amdgcn_s_setprio(1);
#pragma unroll
    for (int mf = 0; mf < 4; ++mf)
#pragma unroll
        for (int nf = 0; nf < 2; ++nf) {
            MFMA16(acc[4 + mf][nf], a[mf][0], bA[nf][0]);
            MFMA16(acc[4 + mf][nf], a[mf][1], bA[nf][1]);
        }
    __builtin_amdgcn_s_setprio(0);

    // tile boundary: DMA landed + own LDS ops drained; then align waves
    asm volatile("s_waitcnt vmcnt(0) lgkmcnt(0)" ::: "memory");
    SBAR;
}

__device__ __forceinline__ void gemm256_core(
    const u16* Aop, const u16* Bop,
    int ld, int nkt,
    u16* A0, u16* A1, u16* B0, u16* B1, f32x4 acc[8][4])
{
    const int tid  = threadIdx.x;
    const int lane = tid & 63;
    const int lr   = lane & 15;
    const int lg   = lane >> 4;
    const int wid  = tid >> 6;
    const int wm   = wid >> 2;        // 0..1
    const int wn   = wid & 3;         // 0..3

    const int swz  = lr & 7;
    const int uc0  = ((0 * 4 + lg) ^ swz) * 8;   // kk=0 read unit (elems)
    const int uc1  = ((1 * 4 + lg) ^ swz) * 8;   // kk=1
    const int arow = wm * 128 + lr;
    const int brow = wn * 64 + lr;

    // prologue: tile 0 -> A0/B0
    stage_half(Aop,                    ld, A0,        tid);
    stage_half(Aop + (size_t)128 * ld, ld, A0 + 8192, tid);
    stage_half(Bop,                    ld, B0,        tid);
    stage_half(Bop + (size_t)128 * ld, ld, B0 + 8192, tid);
    asm volatile("s_waitcnt vmcnt(0)" ::: "memory");
    SBAR;

    for (int G = 0; G < nkt; G += 2) {
        tile_nb(G,     nkt, Aop, Bop, ld, tid, arow, brow, uc0, uc1,
                A0, B0, A1, B1, acc);
        tile_nb(G + 1, nkt, Aop, Bop, ld, tid, arow, brow, uc0, uc1,
                A1, B1, A0, B0, acc);
    }
}

// ---------------------------------------------------------------------------
// Old 128x128 core (kept for the small GEMMs: kv, combine)
// ---------------------------------------------------------------------------
__device__ __forceinline__ void gemm_bt_core(
    const u16* __restrict__ A, const u16* __restrict__ Bm,
    int lda, int ldb, int K, u16* As, u16* Bs, f32x4 acc[4][4])
{
    const int tid  = threadIdx.x;
    const int lane = tid & 63;
    const int lr   = lane & 15;
    const int lg   = lane >> 4;
    const int wid  = tid >> 6;
    const int wr   = (wid >> 1) * 64;
    const int wc   = (wid & 1) * 64;
    for (int kt = 0; kt < K; kt += 64) {
#pragma unroll
        for (int i = 0; i < 4; ++i) {
            int c = tid + i * 256;
            int row = c >> 3, col = (c & 7) * 8;
            gload16(A  + (size_t)row * lda + kt + col, (char*)As + (size_t)c * 16);
            gload16(Bm + (size_t)row * ldb + kt + col, (char*)Bs + (size_t)c * 16);
        }
        __syncthreads();
#pragma unroll
        for (int kk = 0; kk < 2; ++kk) {
            short8 a[4], b[4];
#pragma unroll
            for (int m = 0; m < 4; ++m)
                a[m] = *(const short8*)(As + (wr + m * 16 + lr) * 64 + kk * 32 + lg * 8);
#pragma unroll
            for (int n = 0; n < 4; ++n)
                b[n] = *(const short8*)(Bs + (wc + n * 16 + lr) * 64 + kk * 32 + lg * 8);
#pragma unroll
            for (int m = 0; m < 4; ++m)
#pragma unroll
                for (int n = 0; n < 4; ++n)
                    acc[m][n] = __builtin_amdgcn_mfma_f32_16x16x32_bf16(a[m], b[n], acc[m][n], 0, 0, 0);
        }
        __syncthreads();
    }
}

// ---------------------------------------------------------------------------
// fp32 -> bf16 convert
// ---------------------------------------------------------------------------
__global__ __launch_bounds__(256) void k_f2bf(const float* __restrict__ src,
                                              u16* __restrict__ dst, int n4)
{
    int i = blockIdx.x * blockDim.x + threadIdx.x;
    int stride = gridDim.x * blockDim.x;
    for (int j = i; j < n4; j += stride) {
        float4v f = *(const float4v*)(src + (size_t)j * 4);
        short4v o;
        o.x = (short)f2bf(f.x); o.y = (short)f2bf(f.y);
        o.z = (short)f2bf(f.z); o.w = (short)f2bf(f.w);
        *(short4v*)(dst + (size_t)j * 4) = o;
    }
}

// ---------------------------------------------------------------------------
// GEMM1 (256^2 barrier-minimal): [8192 x 2048] x [8192 x 2048]^T; epilogue
// fuses bias + rotary (q,k), k-scaling, decay-weighted krwT, vT, g.
// ---------------------------------------------------------------------------
__global__ __launch_bounds__(512, 2) void k_gemm1(
    const u16* __restrict__ xb, const u16* __restrict__ wb,
    const float* __restrict__ bq, const float* __restrict__ bk,
    const float* __restrict__ bv, const float* __restrict__ bg,
    const float* __restrict__ sinp, const float* __restrict__ cosp,
    const float* __restrict__ maskp,
    u16* __restrict__ qro, u16* __restrict__ kro, u16* __restrict__ krwT,
    u16* __restrict__ vT, u16* __restrict__ glin)
{
    __shared__ __align__(16) u16 A0[256 * 64];
    __shared__ __align__(16) u16 A1[256 * 64];
    __shared__ __align__(16) u16 B0[256 * 64];
    __shared__ __align__(16) u16 B1[256 * 64];
    f32x4 acc[8][4];
#pragma unroll
    for (int m = 0; m < 8; ++m)
#pragma unroll
        for (int n = 0; n < 4; ++n) acc[m][n] = (f32x4){0.f, 0.f, 0.f, 0.f};

    // T1 bijective XCD swizzle: nwg=1024, 1024%8==0
    int bid = blockIdx.x;
    int swzb = (bid & 7) * 128 + (bid >> 3);
    int mt = swzb >> 5, nt = swzb & 31;          // 32 x 32 tiles of 256

    gemm256_core(xb + (size_t)mt * 256 * ND, wb + (size_t)nt * 256 * ND,
                 ND, ND / 64, A0, A1, B0, B1, acc);

    int tid = threadIdx.x, lane = tid & 63, lr = lane & 15, lg = lane >> 4, wid = tid >> 6;
    int wm = wid >> 2, wn = wid & 3;
    int which = nt >> 3;   // 0:q 1:k 2:v 3:g (uniform per block)

    if (which <= 1) {
        const float* bias = (which == 0) ? bq : bk;
#pragma unroll
        for (int mf = 0; mf < 8; ++mf) {
#pragma unroll
            for (int nf = 0; nf < 4; ++nf) {
#pragma unroll
                for (int r = 0; r < 4; ++r) {
                    int row = mt * 256 + wm * 128 + mf * 16 + lg * 4 + r;
                    int col = nt * 256 + wn * 64 + nf * 16 + lr;
                    int f = col & 2047, h = f >> 7, d = f & 127;
                    int b = row >> 12, t = row & 4095, cn = t >> 9, cl = t & 511;
                    float v = acc[mf][nf][r] + bias[f];
                    if (which == 1) v *= SCALING;
                    float sv = sinp[(size_t)t * NDK + d];
                    float cv = cosp[(size_t)t * NDK + d];
                    float vp = __shfl_xor(v, 1);          // partner feature (col^1)
                    float rot = (lr & 1) ? vp : -vp;      // rotate_every_two
                    float o = v * cv + rot * sv;
                    size_t chbase = (size_t)(b * NNC + cn) * NH + h;
                    if (which == 0) {
                        qro[(chbase * NCL + cl) * NDK + d] = f2bf(o);
                    } else {
                        kro[(chbase * NCL + cl) * NDK + d] = f2bf(o);
                        float w = maskp[((size_t)h * NCL + (NCL - 1)) * NCL + cl];
                        krwT[(chbase * NDK + d) * NCL + cl] = f2bf(o * w);
                    }
                }
            }
        }
    } else {
#pragma unroll
        for (int mf = 0; mf < 8; ++mf) {
#pragma unroll
            for (int nf = 0; nf < 4; ++nf) {
#pragma unroll
                for (int r = 0; r < 4; ++r) {
                    int row = mt * 256 + wm * 128 + mf * 16 + lg * 4 + r;
                    int col = nt * 256 + wn * 64 + nf * 16 + lr;
                    int f = col & 2047;
                    float v = acc[mf][nf][r];
                    if (which == 2) {
                        int h = f >> 7, d = f & 127;
                        int b = row >> 12, t = row & 4095, cn = t >> 9, cl = t & 511;
                        vT[(((size_t)(b * NNC + cn) * NH + h) * NDK + d) * NCL + cl] = f2bf(v + bv[f]);
                    } else {
                        glin[(size_t)row * ND + f] = f2bf(v + bg[f]);
                    }
                }
            }
        }
    }
}

// ---------------------------------------------------------------------------
// GEMM2 (256^2 barrier-minimal): y[8192x2048] x wo[2048x2048]^T + bo -> fp32
// ---------------------------------------------------------------------------
__global__ __launch_bounds__(512, 2) void k_gemm2(
    const u16* __restrict__ y, const u16* __restrict__ wob,
    const float* __restrict__ bo, float* __restrict__ out)
{
    __shared__ __align__(16) u16 A0[256 * 64];
    __shared__ __align__(16) u16 A1[256 * 64];
    __shared__ __align__(16) u16 B0[256 * 64];
    __shared__ __align__(16) u16 B1[256 * 64];
    f32x4 acc[8][4];
#pragma unroll
    for (int m = 0; m < 8; ++m)
#pragma unroll
        for (int n = 0; n < 4; ++n) acc[m][n] = (f32x4){0.f, 0.f, 0.f, 0.f};

    // nwg = 256, 256%8==0
    int bid = blockIdx.x;
    int swzb = (bid & 7) * 32 + (bid >> 3);
    int mt = swzb >> 3, nt = swzb & 7;           // 32 x 8 tiles of 256

    gemm256_core(y + (size_t)mt * 256 * ND, wob + (size_t)nt * 256 * ND,
                 ND, ND / 64, A0, A1, B0, B1, acc);

    int tid = threadIdx.x, lane = tid & 63, lr = lane & 15, lg = lane >> 4, wid = tid >> 6;
    int wm = wid >> 2, wn = wid & 3;
#pragma unroll
    for (int mf = 0; mf < 8; ++mf)
#pragma unroll
        for (int nf = 0; nf < 4; ++nf)
#pragma unroll
            for (int r = 0; r < 4; ++r) {
                int row = mt * 256 + wm * 128 + mf * 16 + lg * 4 + r;
                int col = nt * 256 + wn * 64 + nf * 16 + lr;
                out[(size_t)row * ND + col] = acc[mf][nf][r] + bo[col];
            }
}

// ---------------------------------------------------------------------------
// Inner retention (unchanged): P = (Q K^T)*mask ; s=row|P|sum ; iraw = P @ V.
// ---------------------------------------------------------------------------
__global__ __launch_bounds__(256) void k_inner(
    const u16* __restrict__ qr, const u16* __restrict__ kr,
    const u16* __restrict__ vT, const float* __restrict__ mask,
    float* __restrict__ iraw, float* __restrict__ iscale)
{
    __shared__ __align__(16) u16 Qs[128 * 128];
    __shared__ __align__(16) u16 Ks[32 * 128];
    __shared__ __align__(16) u16 Vs[128 * 32];
    __shared__ __align__(16) u16 Ps[4][32 * 32];
    __shared__ float sl[128];

    int qt = blockIdx.x, bnh = blockIdx.y;
    int h = bnh & 15;
    const u16* Q = qr + (size_t)bnh * NCL * NDK + (size_t)qt * 128 * NDK;
    const u16* K = kr + (size_t)bnh * NCL * NDK;
    const u16* V = vT + (size_t)bnh * NDK * NCL;
    const float* M = mask + (size_t)h * NCL * NCL + (size_t)qt * 128 * NCL;

    int tid = threadIdx.x, lane = tid & 63, lr = lane & 15, lg = lane >> 4, wid = tid >> 6;
    if (tid < 128) sl[tid] = 0.f;
#pragma unroll
    for (int i = 0; i < 8; ++i) {
        int c = tid + i * 256;
        gload16(Q + (size_t)c * 8, (char*)Qs + (size_t)c * 16);
    }
    __syncthreads();

    short8 aq[2][4];
#pragma unroll
    for (int i = 0; i < 2; ++i)
#pragma unroll
        for (int kk = 0; kk < 4; ++kk)
            aq[i][kk] = *(const short8*)(Qs + (wid * 32 + i * 16 + lr) * 128 + kk * 32 + lg * 8);

    f32x4 acc[2][8];
#pragma unroll
    for (int i = 0; i < 2; ++i)
#pragma unroll
        for (int n = 0; n < 8; ++n) acc[i][n] = (f32x4){0.f, 0.f, 0.f, 0.f};

    int msteps = qt * 4 + 4;
    for (int ms = 0; ms < msteps; ++ms) {
        int mb = ms * 32;
#pragma unroll
        for (int i = 0; i < 2; ++i) {
            int c = tid + i * 256;
            int row = c >> 4, cc = (c & 15) * 8;
            gload16(K + (size_t)(mb + row) * NDK + cc, (char*)Ks + (size_t)c * 16);
        }
#pragma unroll
        for (int i = 0; i < 2; ++i) {
            int c = tid + i * 256;
            int row = c >> 2, cc = (c & 3) * 8;
            gload16(V + (size_t)row * NCL + mb + cc, (char*)Vs + (size_t)c * 16);
        }
        __syncthreads();

        f32x4 pa[2][2];
#pragma unroll
        for (int i = 0; i < 2; ++i) { pa[i][0] = (f32x4){0.f,0.f,0.f,0.f}; pa[i][1] = (f32x4){0.f,0.f,0.f,0.f}; }
#pragma unroll
        for (int kk = 0; kk < 4; ++kk) {
            short8 bk0 = *(const short8*)(Ks + (lr) * 128 + kk * 32 + lg * 8);
            short8 bk1 = *(const short8*)(Ks + (16 + lr) * 128 + kk * 32 + lg * 8);
#pragma unroll
            for (int i = 0; i < 2; ++i) {
                pa[i][0] = __builtin_amdgcn_mfma_f32_16x16x32_bf16(aq[i][kk], bk0, pa[i][0], 0, 0, 0);
                pa[i][1] = __builtin_amdgcn_mfma_f32_16x16x32_bf16(aq[i][kk], bk1, pa[i][1], 0, 0, 0);
            }
        }
#pragma unroll
        for (int i = 0; i < 2; ++i) {
#pragma unroll
            for (int r = 0; r < 4; ++r) {
                int rloc = i * 16 + lg * 4 + r;
                int row128 = wid * 32 + rloc;
                float m0 = M[(size_t)row128 * NCL + mb + lr];
                float m1 = M[(size_t)row128 * NCL + mb + 16 + lr];
                float p0 = pa[i][0][r] * m0;
                float p1 = pa[i][1][r] * m1;
                float ss = fabsf(p0) + fabsf(p1);
                ss += __shfl_xor(ss, 1); ss += __shfl_xor(ss, 2);
                ss += __shfl_xor(ss, 4); ss += __shfl_xor(ss, 8);
                if (lr == 0) sl[row128] += ss;
                Ps[wid][rloc * 32 + lr]      = f2bf(p0);
                Ps[wid][rloc * 32 + 16 + lr] = f2bf(p1);
            }
        }
        __syncthreads();

        short8 ap[2];
#pragma unroll
        for (int i = 0; i < 2; ++i)
            ap[i] = *(const short8*)(Ps[wid] + (i * 16 + lr) * 32 + lg * 8);
#pragma unroll
        for (int n = 0; n < 8; ++n) {
            short8 bv8 = *(const short8*)(Vs + (n * 16 + lr) * 32 + lg * 8);
#pragma unroll
            for (int i = 0; i < 2; ++i)
                acc[i][n] = __builtin_amdgcn_mfma_f32_16x16x32_bf16(ap[i], bv8, acc[i][n], 0, 0, 0);
        }
        __syncthreads();
    }

    float* OR = iraw + ((size_t)bnh * NCL + (size_t)qt * 128) * NDK;
#pragma unroll
    for (int i = 0; i < 2; ++i)
#pragma unroll
        for (int n = 0; n < 8; ++n)
#pragma unroll
            for (int r = 0; r < 4; ++r) {
                int row = wid * 32 + i * 16 + lg * 4 + r;
                int col = n * 16 + lr;
                OR[(size_t)row * NDK + col] = acc[i][n][r];
            }
    __syncthreads();
    if (tid < 128) iscale[(size_t)bnh * NCL + qt * 128 + tid] = fmaxf(1.f, sl[tid]);
}

// ---------------------------------------------------------------------------
// kv_i[k][d] = sum_l krw[l][k] * v[l][d]
// ---------------------------------------------------------------------------
__global__ __launch_bounds__(256) void k_kv(
    const u16* __restrict__ krwT, const u16* __restrict__ vT, float* __restrict__ kvi)
{
    __shared__ __align__(16) u16 As[128 * 64];
    __shared__ __align__(16) u16 Bs[128 * 64];
    f32x4 acc[4][4];
#pragma unroll
    for (int m = 0; m < 4; ++m)
#pragma unroll
        for (int n = 0; n < 4; ++n) acc[m][n] = (f32x4){0.f, 0.f, 0.f, 0.f};

    int bnh = blockIdx.x;
    gemm_bt_core(krwT + (size_t)bnh * NDK * NCL, vT + (size_t)bnh * NDK * NCL,
                 NCL, NCL, NCL, As, Bs, acc);

    int tid = threadIdx.x, lane = tid & 63, lr = lane & 15, lg = lane >> 4, wid = tid >> 6;
    int wr = (wid >> 1) * 64, wc = (wid & 1) * 64;
    float* O = kvi + (size_t)bnh * NDK * NDK;
#pragma unroll
    for (int m = 0; m < 4; ++m)
#pragma unroll
        for (int n = 0; n < 4; ++n)
#pragma unroll
            for (int r = 0; r < 4; ++r) {
                int row = wr + m * 16 + lg * 4 + r;
                int col = wc + n * 16 + lr;
                O[(size_t)row * NDK + col] = acc[m][n][r];
            }
}

// ---------------------------------------------------------------------------
// Recurrent scan over chunks (unchanged)
// ---------------------------------------------------------------------------
__global__ __launch_bounds__(256) void k_scan(
    const float* __restrict__ kvi, const float* __restrict__ cdec,
    u16* __restrict__ kvrT, float* __restrict__ csc)
{
    int bh = blockIdx.x;
    int b = bh >> 4, h = bh & 15;
    float cd = cdec[h];
    int tid = threadIdx.x;
    int col = tid & 127;
    int r0 = (tid >> 7) * 64;
    float st[64];
#pragma unroll
    for (int i = 0; i < 64; ++i) st[i] = 0.f;
    float scale = 1.f;
    __shared__ float cs[128];
    __shared__ float scsh;

    for (int n = 0; n < NNC; ++n) {
        size_t idx = (size_t)((b * NNC + n) * NH + h);
        size_t kb = idx * (NDK * NDK);
        float inv = 1.f / scale;
#pragma unroll
        for (int i = 0; i < 64; ++i)
            kvrT[kb + (size_t)col * NDK + r0 + i] = f2bf(st[i] * inv);
        if (tid == 0) csc[idx] = scale;

        const float* KV = kvi + kb;
        float colsum = 0.f;
#pragma unroll
        for (int i = 0; i < 64; ++i) {
            float xv = st[i] * cd + KV[(size_t)(r0 + i) * NDK + col];
            st[i] = xv;
            colsum += fabsf(xv);
        }
        __syncthreads();
        if (tid < 128) cs[tid] = 0.f;
        __syncthreads();
        atomicAdd(&cs[col], colsum);
        __syncthreads();
        if (tid == 0) {
            float mx = cs[0];
            for (int i = 1; i < 128; ++i) mx = fmaxf(mx, cs[i]);
            scsh = fmaxf(1.f, mx);
        }
        __syncthreads();
        scale = scsh;
    }
}

// ---------------------------------------------------------------------------
// Combine (unchanged)
// ---------------------------------------------------------------------------
__global__ __launch_bounds__(256) void k_combine(
    const u16* __restrict__ qr, const u16* __restrict__ kvrT,
    const float* __restrict__ iraw, const float* __restrict__ iscale,
    const float* __restrict__ cscale, const float* __restrict__ idecay,
    const u16* __restrict__ glin, u16* __restrict__ y)
{
    __shared__ __align__(16) u16 As[128 * 64];
    __shared__ __align__(16) u16 Bs[128 * 64];
    __shared__ float ssum[128];
    __shared__ float ssq[128];
    f32x4 acc[4][4];
#pragma unroll
    for (int m = 0; m < 4; ++m)
#pragma unroll
        for (int n = 0; n < 4; ++n) acc[m][n] = (f32x4){0.f, 0.f, 0.f, 0.f};

    int qt = blockIdx.x, bnh = blockIdx.y;
    int b = bnh >> 7, cn = (bnh >> 4) & 7, h = bnh & 15;
    gemm_bt_core(qr + (size_t)bnh * NCL * NDK + (size_t)qt * 128 * NDK,
                 kvrT + (size_t)bnh * NDK * NDK, NDK, NDK, NDK, As, Bs, acc);

    int tid = threadIdx.x, lane = tid & 63, lr = lane & 15, lg = lane >> 4, wid = tid >> 6;
    int wr = (wid >> 1) * 64, wc = (wid & 1) * 64;
    if (tid < 128) { ssum[tid] = 0.f; ssq[tid] = 0.f; }
    __syncthreads();
    float csv = cscale[bnh];

#pragma unroll
    for (int m = 0; m < 4; ++m) {
#pragma unroll
        for (int r = 0; r < 4; ++r) {
            int rloc = wr + m * 16 + lg * 4 + r;
            int l = qt * 128 + rloc;
            float isc = iscale[(size_t)bnh * NCL + l];
            float all = fmaxf(isc, csv);
            float c1 = 1.f / all;
            float c2 = (csv / all) * idecay[h * NCL + l];
            const float* ir = iraw + ((size_t)bnh * NCL + l) * NDK;
            float lsum = 0.f, lsq = 0.f;
#pragma unroll
            for (int n = 0; n < 4; ++n) {
                int col = wc + n * 16 + lr;
                float v = ir[col] * c1 + acc[m][n][r] * c2;
                acc[m][n][r] = v;
                lsum += v; lsq += v * v;
            }
            lsum += __shfl_xor(lsum, 1); lsum += __shfl_xor(lsum, 2);
            lsum += __shfl_xor(lsum, 4); lsum += __shfl_xor(lsum, 8);
            lsq  += __shfl_xor(lsq, 1);  lsq  += __shfl_xor(lsq, 2);
            lsq  += __shfl_xor(lsq, 4);  lsq  += __shfl_xor(lsq, 8);
            if (lr == 0) { atomicAdd(&ssum[rloc], lsum); atomicAdd(&ssq[rloc], lsq); }
        }
    }
    __syncthreads();
#pragma unroll
    for (int m = 0; m < 4; ++m) {
#pragma unroll
        for (int r = 0; r < 4; ++r) {
            int rloc = wr + m * 16 + lg * 4 + r;
            int l = qt * 128 + rloc;
            float mu = ssum[rloc] * (1.f / 128.f);
            float var = ssq[rloc] * (1.f / 128.f) - mu * mu;
            float rstd = rsqrtf(fmaxf(var, 0.f) + 1e-6f);
            int t = cn * NCL + l;
            size_t obase = ((size_t)(b * NT + t)) * ND + (size_t)h * NDK;
#pragma unroll
            for (int n = 0; n < 4; ++n) {
                int col = wc + n * 16 + lr;
                float gv = bf2f(glin[obase + col]);
                float sg = gv / (1.f + expf(-gv));
                float ov = (acc[m][n][r] - mu) * rstd * sg;
                y[obase + col] = f2bf(ov);
            }
        }
    }
}

// ---------------------------------------------------------------------------
extern "C" void kernel_launch(void* const* d_in, const int* in_sizes, int n_in,
                              void* d_out, int out_size, void* d_ws, size_t ws_size,
                              hipStream_t stream)
{
    const float* x    = (const float*)d_in[0];
    const float* sinp = (const float*)d_in[1];
    const float* cosp = (const float*)d_in[2];
    const float* mask = (const float*)d_in[3];
    const float* cdec = (const float*)d_in[4];
    const float* idec = (const float*)d_in[5];
    const float* wq   = (const float*)d_in[6];
    const float* bq   = (const float*)d_in[7];
    const float* wk   = (const float*)d_in[8];
    const float* bk   = (const float*)d_in[9];
    const float* wv   = (const float*)d_in[10];
    const float* bv   = (const float*)d_in[11];
    const float* wg   = (const float*)d_in[12];
    const float* bg   = (const float*)d_in[13];
    const float* wo   = (const float*)d_in[14];
    const float* bo   = (const float*)d_in[15];
    float* out = (float*)d_out;

    // Workspace layout (~248 MB), lifetime-based aliasing (see round-2 notes)
    char* ws = (char*)d_ws;
    u16*   XB   = (u16*)(ws + 0);
    u16*   WB   = (u16*)(ws + 33554432);
    u16*   WOB  = (u16*)(ws + 67108864);
    u16*   QR   = (u16*)(ws + 75497472);
    u16*   KR   = (u16*)(ws + 109051904);
    u16*   KRWT = (u16*)(ws + 142606336);
    u16*   VT   = (u16*)(ws + 176160768);
    u16*   GLIN = (u16*)(ws + 209715200);
    float* KVI  = (float*)(ws + 243269632);
    float* CSC  = (float*)(ws + 260046848);
    float* IRAW = (float*)(ws + 0);           // alias XB+WB (dead after gemm1)
    u16*   Y    = KR;                         // alias KR (dead after inner)
    u16*   KVRT = KRWT;                       // alias KRWT (dead after kv)
    float* ISC  = (float*)(ws + 243269632);   // alias KVI (dead after scan)

    k_f2bf<<<2048, 256, 0, stream>>>(x, XB, 4194304);
    k_f2bf<<<1024, 256, 0, stream>>>(wq, WB,            1048576);
    k_f2bf<<<1024, 256, 0, stream>>>(wk, WB + 4194304,  1048576);
    k_f2bf<<<1024, 256, 0, stream>>>(wv, WB + 8388608,  1048576);
    k_f2bf<<<1024, 256, 0, stream>>>(wg, WB + 12582912, 1048576);
    k_f2bf<<<1024, 256, 0, stream>>>(wo, WOB,           1048576);

    k_gemm1<<<1024, 512, 0, stream>>>(XB, WB, bq, bk, bv, bg, sinp, cosp, mask,
                                      QR, KR, KRWT, VT, GLIN);
    k_kv<<<256, 256, 0, stream>>>(KRWT, VT, KVI);
    k_scan<<<32, 256, 0, stream>>>(KVI, cdec, KVRT, CSC);
    k_inner<<<dim3(4, 256), 256, 0, stream>>>(QR, KR, VT, mask, IRAW, ISC);
    k_combine<<<dim3(4, 256), 256, 0, stream>>>(QR, KVRT, IRAW, ISC, CSC, idec, GLIN, Y);
    k_gemm2<<<256, 512, 0, stream>>>(Y, WOB, bo, out);
}